// Round 13
// baseline (729.121 us; speedup 1.0000x reference)
//
#include <hip/hip_runtime.h>

typedef __attribute__((ext_vector_type(4))) float f32x4;
typedef __attribute__((ext_vector_type(16))) float f32x16;
typedef __attribute__((ext_vector_type(8))) short s16x8;
typedef __attribute__((ext_vector_type(4))) unsigned short u16x4;

#define B_    8
#define L_    512
#define LC_   2048
#define EMBD  1024

__device__ __forceinline__ float b2f(unsigned short u) {
  unsigned int i = ((unsigned int)u) << 16;
  float f; __builtin_memcpy(&f, &i, 4); return f;
}
__device__ __forceinline__ unsigned short f2b(float f) {
  unsigned int i; __builtin_memcpy(&i, &f, 4);
  unsigned int r = i + 0x7FFFu + ((i >> 16) & 1u);
  return (unsigned short)(r >> 16);
}

#define GLL16(g, l)                                                         \
  __builtin_amdgcn_global_load_lds(                                         \
      (__attribute__((address_space(1))) void*)(g),                         \
      (__attribute__((address_space(3))) void*)(l), 16, 0, 0)

#define VMCNT6() asm volatile("s_waitcnt vmcnt(6)" ::: "memory")
#define VMCNT0() asm volatile("s_waitcnt vmcnt(0)" ::: "memory")
#define LGKM0()  asm volatile("s_waitcnt lgkmcnt(0)" ::: "memory")

// ---------------------------------------------------------------- converts (all 9 in one launch)
__global__ __launch_bounds__(256) void convert9(
    const float* s0, const float* s1, const float* s2, const float* s3,
    const float* s4, const float* s5, const float* s6, const float* s7,
    const float* s8,
    unsigned short* d0, unsigned short* d1, unsigned short* d2,
    unsigned short* d3, unsigned short* d4, unsigned short* d5,
    unsigned short* d6, unsigned short* d7, unsigned short* d8) {
  int bk = blockIdx.x;
  const float* s; unsigned short* d; int base;
  if      (bk <  2048) { s = s0; d = d0; base = 0; }
  else if (bk <  2112) { s = s1; d = d1; base = 2048; }
  else if (bk <  2176) { s = s2; d = d2; base = 2112; }
  else if (bk <  4224) { s = s3; d = d3; base = 2176; }
  else if (bk <  8320) { s = s4; d = d4; base = 4224; }
  else if (bk < 12416) { s = s5; d = d5; base = 8320; }
  else if (bk < 16512) { s = s6; d = d6; base = 12416; }
  else if (bk < 20608) { s = s7; d = d7; base = 16512; }
  else                 { s = s8; d = d8; base = 20608; }
  int i = (bk - base) * 256 + threadIdx.x;
  float4 v = ((const float4*)s)[i];
  u16x4 o = { f2b(v.x), f2b(v.y), f2b(v.z), f2b(v.w) };
  ((u16x4*)d)[i] = o;
}

// ---------------------------------------------------------------- rmsnorm
__global__ __launch_bounds__(256) void rmsnorm_kernel(
    const float* __restrict__ x, const float* __restrict__ w,
    unsigned short* __restrict__ out) {
  int row = blockIdx.x;
  int tid = threadIdx.x;
  float4 v = ((const float4*)(x + (size_t)row * EMBD))[tid];
  float ss = v.x*v.x + v.y*v.y + v.z*v.z + v.w*v.w;
#pragma unroll
  for (int o = 1; o < 64; o <<= 1) ss += __shfl_xor(ss, o);
  __shared__ float red[4];
  if ((tid & 63) == 0) red[tid >> 6] = ss;
  __syncthreads();
  float tot = red[0] + red[1] + red[2] + red[3];
  float rs = rsqrtf(tot * (1.0f / EMBD) + 1.1920928955078125e-07f);
  float4 wv = ((const float4*)w)[tid];
  u16x4 o = { f2b(v.x*rs*wv.x), f2b(v.y*rs*wv.y), f2b(v.z*rs*wv.z), f2b(v.w*rs*wv.w) };
  ((u16x4*)(out + (size_t)row * EMBD))[tid] = o;
}

// ---------------------------------------------------------------- rope (in-place on [4096][2048] bf16)
__global__ __launch_bounds__(256) void rope_kernel(unsigned short* __restrict__ q) {
  int idx = blockIdx.x * 256 + threadIdx.x;
  int i   = idx & 127;
  int h   = (idx >> 7) & 7;
  int row = idx >> 10;
  int l   = row & (L_ - 1);
  size_t base = (size_t)row * 2048 + h * 256 + i;
  float x1 = b2f(q[base]);
  float x2 = b2f(q[base + 128]);
  float ts  = powf(10000.0f, (float)i * (2.0f / 256.0f));
  float rad = (float)l / ts;
  float s, c;
  sincosf(rad, &s, &c);
  q[base]       = f2b(x1 * c - x2 * s);
  q[base + 128] = f2b(x2 * c + x1 * s);
}

// ---------------------------------------------------------------- NT GEMM 128x128 (2-barrier)
template <int ADD_RES, int OUT_BF16>
__global__ __launch_bounds__(256, 2) void gemm_nt(
    const unsigned short* __restrict__ A, const unsigned short* __restrict__ Bw,
    const float* __restrict__ Res, void* __restrict__ C, int M, int N, int K) {
  __shared__ unsigned short As[128 * 64];
  __shared__ unsigned short Bs[128 * 64];
  const int tid = threadIdx.x;
  const int lane = tid & 63, wid = tid >> 6;
  const int l15 = lane & 15, l4 = lane >> 4;
  const int wr = wid >> 1, wc = wid & 1;
  const int m0 = blockIdx.y * 128, n0 = blockIdx.x * 128;

  const f32x4 fz = {0.f, 0.f, 0.f, 0.f};
  f32x4 acc[4][4];
#pragma unroll
  for (int i = 0; i < 4; ++i)
#pragma unroll
    for (int j = 0; j < 4; ++j) acc[i][j] = fz;

  for (int k0 = 0; k0 < K; k0 += 64) {
    __syncthreads();
#pragma unroll
    for (int i = 0; i < 4; ++i) {
      int Li = i * 4096 + tid * 16;
      int row = Li >> 7;
      int kb = (Li & 127) ^ ((row & 7) << 4);
      GLL16((const char*)(A + (size_t)(m0 + row) * K + k0) + kb, (char*)As + Li);
      GLL16((const char*)(Bw + (size_t)(n0 + row) * K + k0) + kb, (char*)Bs + Li);
    }
    __syncthreads();
#pragma unroll
    for (int kk = 0; kk < 2; ++kk) {
      s16x8 af[4], bfr[4];
#pragma unroll
      for (int mi = 0; mi < 4; ++mi) {
        int row = wr * 64 + mi * 16 + l15;
        int kb = (kk * 64 + l4 * 16) ^ ((row & 7) << 4);
        af[mi] = *(const s16x8*)((const char*)As + row * 128 + kb);
      }
#pragma unroll
      for (int ni = 0; ni < 4; ++ni) {
        int row = wc * 64 + ni * 16 + l15;
        int kb = (kk * 64 + l4 * 16) ^ ((row & 7) << 4);
        bfr[ni] = *(const s16x8*)((const char*)Bs + row * 128 + kb);
      }
#pragma unroll
      for (int mi = 0; mi < 4; ++mi)
#pragma unroll
        for (int ni = 0; ni < 4; ++ni)
          acc[mi][ni] = __builtin_amdgcn_mfma_f32_16x16x32_bf16(
              af[mi], bfr[ni], acc[mi][ni], 0, 0, 0);
    }
  }
#pragma unroll
  for (int mi = 0; mi < 4; ++mi) {
#pragma unroll
    for (int r = 0; r < 4; ++r) {
      int grow = m0 + wr * 64 + mi * 16 + l4 * 4 + r;
      size_t base = (size_t)grow * N + n0 + wc * 64 + l15;
#pragma unroll
      for (int ni = 0; ni < 4; ++ni) {
        float v = acc[mi][ni][r];
        size_t idx = base + ni * 16;
        if (ADD_RES) v += Res[idx];
        if (OUT_BF16) ((unsigned short*)C)[idx] = f2b(v);
        else          ((float*)C)[idx] = v;
      }
    }
  }
}

// ---------------------------------------------------------------- NT GEMM 64x128 (512-block grids, 2/CU)
template <int ADD_RES, int OUT_BF16>
__global__ __launch_bounds__(256, 2) void gemm_nt64(
    const unsigned short* __restrict__ A, const unsigned short* __restrict__ Bw,
    const float* __restrict__ Res, void* __restrict__ C, int M, int N, int K) {
  __shared__ unsigned short As[64 * 64];
  __shared__ unsigned short Bs[128 * 64];
  const int tid = threadIdx.x;
  const int lane = tid & 63, wid = tid >> 6;
  const int l15 = lane & 15, l4 = lane >> 4;
  const int wr = wid >> 1, wc = wid & 1;
  const int m0 = blockIdx.y * 64, n0 = blockIdx.x * 128;

  const f32x4 fz = {0.f, 0.f, 0.f, 0.f};
  f32x4 acc[2][4];
#pragma unroll
  for (int i = 0; i < 2; ++i)
#pragma unroll
    for (int j = 0; j < 4; ++j) acc[i][j] = fz;

  for (int k0 = 0; k0 < K; k0 += 64) {
    __syncthreads();
#pragma unroll
    for (int i = 0; i < 2; ++i) {
      int Li = i * 4096 + tid * 16;
      int row = Li >> 7;
      int kb = (Li & 127) ^ ((row & 7) << 4);
      GLL16((const char*)(A + (size_t)(m0 + row) * K + k0) + kb, (char*)As + Li);
    }
#pragma unroll
    for (int i = 0; i < 4; ++i) {
      int Li = i * 4096 + tid * 16;
      int row = Li >> 7;
      int kb = (Li & 127) ^ ((row & 7) << 4);
      GLL16((const char*)(Bw + (size_t)(n0 + row) * K + k0) + kb, (char*)Bs + Li);
    }
    __syncthreads();
#pragma unroll
    for (int kk = 0; kk < 2; ++kk) {
      s16x8 af[2], bfr[4];
#pragma unroll
      for (int mi = 0; mi < 2; ++mi) {
        int row = wr * 32 + mi * 16 + l15;
        int kb = (kk * 64 + l4 * 16) ^ ((row & 7) << 4);
        af[mi] = *(const s16x8*)((const char*)As + row * 128 + kb);
      }
#pragma unroll
      for (int ni = 0; ni < 4; ++ni) {
        int row = wc * 64 + ni * 16 + l15;
        int kb = (kk * 64 + l4 * 16) ^ ((row & 7) << 4);
        bfr[ni] = *(const s16x8*)((const char*)Bs + row * 128 + kb);
      }
#pragma unroll
      for (int mi = 0; mi < 2; ++mi)
#pragma unroll
        for (int ni = 0; ni < 4; ++ni)
          acc[mi][ni] = __builtin_amdgcn_mfma_f32_16x16x32_bf16(
              af[mi], bfr[ni], acc[mi][ni], 0, 0, 0);
    }
  }
#pragma unroll
  for (int mi = 0; mi < 2; ++mi) {
#pragma unroll
    for (int r = 0; r < 4; ++r) {
      int grow = m0 + wr * 32 + mi * 16 + l4 * 4 + r;
      size_t base = (size_t)grow * N + n0 + wc * 64 + l15;
#pragma unroll
      for (int ni = 0; ni < 4; ++ni) {
        float v = acc[mi][ni][r];
        size_t idx = base + ni * 16;
        if (ADD_RES) v += Res[idx];
        if (OUT_BF16) ((unsigned short*)C)[idx] = f2b(v);
        else          ((float*)C)[idx] = v;
      }
    }
  }
}

// ---------------------------------------------------------------- 256x256 8-phase GEMM (T1..T5; optional fused silu(g)*acc)
template <int SWIGLU>
__global__ __launch_bounds__(512, 2) void gemm256(
    const unsigned short* __restrict__ A, const unsigned short* __restrict__ Bw,
    const unsigned short* __restrict__ G, unsigned short* __restrict__ C,
    int M, int N, int K) {
  extern __shared__ char smem[];
  const int tid = threadIdx.x;
  const int lane = tid & 63;
  const int wid = tid >> 6;
  const int wr = wid >> 2, wc = wid & 3;
  const int l15 = lane & 15, g = lane >> 4;
  int flat = blockIdx.y * 16 + blockIdx.x;
  flat = (flat & 7) * 32 + (flat >> 3);
  const int m0 = (flat >> 4) * 256, n0 = (flat & 15) * 256;
  const int T = K >> 6;
  const int swz = (l15 & 7) << 4;

  auto stage = [&](int t, int mat, int half) {
    char* dst = smem + mat * 65536 + (t & 1) * 32768 + half * 16384;
    const unsigned short* src = (mat ? Bw + (size_t)(n0 + half * 128) * K
                                     : A + (size_t)(m0 + half * 128) * K) + t * 64;
#pragma unroll
    for (int i = 0; i < 2; ++i) {
      int Li = i * 8192 + tid * 16;
      int row = Li >> 7;
      int kb = (Li & 127) ^ ((row & 7) << 4);
      GLL16((const char*)(src + (size_t)row * K) + kb, dst + Li);
    }
  };

  const f32x4 fz = {0.f, 0.f, 0.f, 0.f};
  f32x4 acc[2][2][4][2];
#pragma unroll
  for (int ms = 0; ms < 2; ++ms)
#pragma unroll
    for (int ns = 0; ns < 2; ++ns)
#pragma unroll
      for (int mi = 0; mi < 4; ++mi)
#pragma unroll
        for (int ni = 0; ni < 2; ++ni) acc[ms][ns][mi][ni] = fz;

  stage(0, 1, 0); stage(0, 1, 1); stage(0, 0, 0); stage(0, 0, 1);
  stage(1, 1, 0); stage(1, 1, 1); stage(1, 0, 0);
  VMCNT6();
  __builtin_amdgcn_s_barrier();

  for (int t = 0; t < T; ++t) {
    char* Ab = smem + (t & 1) * 32768 + wr * 16384;
    char* Bb = smem + 65536 + (t & 1) * 32768 + (wc >> 1) * 16384;
    const int bn = (wc & 1) * 64;
    s16x8 a[4][2], b0[2][2], b1[2][2];

#pragma unroll
    for (int mi = 0; mi < 4; ++mi) {
      int row = mi * 16 + l15;
#pragma unroll
      for (int kk = 0; kk < 2; ++kk)
        a[mi][kk] = *(const s16x8*)(Ab + row * 128 + ((kk * 64 + g * 16) ^ swz));
    }
#pragma unroll
    for (int ni = 0; ni < 2; ++ni) {
      int r0 = (bn + ni * 16 + l15) * 128;
      int r1 = (bn + 32 + ni * 16 + l15) * 128;
#pragma unroll
      for (int kk = 0; kk < 2; ++kk) {
        int ko = (kk * 64 + g * 16) ^ swz;
        b0[ni][kk] = *(const s16x8*)(Bb + r0 + ko);
        b1[ni][kk] = *(const s16x8*)(Bb + r1 + ko);
      }
    }
    if (t + 1 < T) stage(t + 1, 0, 1);
    __builtin_amdgcn_s_barrier();
    LGKM0();
    __builtin_amdgcn_sched_barrier(0);
    __builtin_amdgcn_s_setprio(1);
#pragma unroll
    for (int mi = 0; mi < 4; ++mi)
#pragma unroll
      for (int ni = 0; ni < 2; ++ni)
#pragma unroll
        for (int kk = 0; kk < 2; ++kk)
          acc[0][0][mi][ni] = __builtin_amdgcn_mfma_f32_16x16x32_bf16(
              a[mi][kk], b0[ni][kk], acc[0][0][mi][ni], 0, 0, 0);
    __builtin_amdgcn_s_setprio(0);
    __builtin_amdgcn_s_barrier();

    if (t + 2 < T) stage(t + 2, 1, 0);
    __builtin_amdgcn_s_barrier();
    __builtin_amdgcn_s_setprio(1);
#pragma unroll
    for (int mi = 0; mi < 4; ++mi)
#pragma unroll
      for (int ni = 0; ni < 2; ++ni)
#pragma unroll
        for (int kk = 0; kk < 2; ++kk)
          acc[0][1][mi][ni] = __builtin_amdgcn_mfma_f32_16x16x32_bf16(
              a[mi][kk], b1[ni][kk], acc[0][1][mi][ni], 0, 0, 0);
    __builtin_amdgcn_s_setprio(0);
    __builtin_amdgcn_s_barrier();

#pragma unroll
    for (int mi = 0; mi < 4; ++mi) {
      int row = 64 + mi * 16 + l15;
#pragma unroll
      for (int kk = 0; kk < 2; ++kk)
        a[mi][kk] = *(const s16x8*)(Ab + row * 128 + ((kk * 64 + g * 16) ^ swz));
    }
    if (t + 2 < T) stage(t + 2, 1, 1);
    __builtin_amdgcn_s_barrier();
    LGKM0();
    __builtin_amdgcn_sched_barrier(0);
    __builtin_amdgcn_s_setprio(1);
#pragma unroll
    for (int mi = 0; mi < 4; ++mi)
#pragma unroll
      for (int ni = 0; ni < 2; ++ni)
#pragma unroll
        for (int kk = 0; kk < 2; ++kk)
          acc[1][0][mi][ni] = __builtin_amdgcn_mfma_f32_16x16x32_bf16(
              a[mi][kk], b0[ni][kk], acc[1][0][mi][ni], 0, 0, 0);
    __builtin_amdgcn_s_setprio(0);
    __builtin_amdgcn_s_barrier();

    if (t + 2 < T) { stage(t + 2, 0, 0); VMCNT6(); }
    else           { VMCNT0(); }
    __builtin_amdgcn_s_barrier();
    __builtin_amdgcn_s_setprio(1);
#pragma unroll
    for (int mi = 0; mi < 4; ++mi)
#pragma unroll
      for (int ni = 0; ni < 2; ++ni)
#pragma unroll
        for (int kk = 0; kk < 2; ++kk)
          acc[1][1][mi][ni] = __builtin_amdgcn_mfma_f32_16x16x32_bf16(
              a[mi][kk], b1[ni][kk], acc[1][1][mi][ni], 0, 0, 0);
    __builtin_amdgcn_s_setprio(0);
    __builtin_amdgcn_s_barrier();
  }

#pragma unroll
  for (int ms = 0; ms < 2; ++ms)
#pragma unroll
    for (int mi = 0; mi < 4; ++mi)
#pragma unroll
      for (int r = 0; r < 4; ++r) {
        int grow = m0 + wr * 128 + ms * 64 + mi * 16 + g * 4 + r;
        size_t base = (size_t)grow * N + n0 + wc * 64;
#pragma unroll
        for (int ns = 0; ns < 2; ++ns)
#pragma unroll
          for (int ni = 0; ni < 2; ++ni) {
            size_t idx = base + ns * 32 + ni * 16 + l15;
            float v = acc[ms][ns][mi][ni][r];
            if (SWIGLU) {
              float gf = b2f(G[idx]);
              v *= gf / (1.0f + __expf(-gf));
            }
            C[idx] = f2b(v);
          }
      }
}

// ---------------------------------------------------------------- fused attention (32x32x16, O^T, zero-shuffle, 2 blocks/CU)
// grid (qt=4, h=8, b=8) = 256 blocks, 256 thr = 4 waves x 32 q-rows; 32 KV
// tiles/block. R12 measured VGPR=244 <= 256 -> (256,2) gives 2 waves/SIMD =
// 2 blocks/CU (128KB LDS of 160): independent barrier domains restore the
// wave-overlap R12 lost, on top of halved LDS reads (conflicts 1.05e7).
// K staged with kv bits 2<->3 swapped so lane's packed S^T values form PV
// B-frags directly; O^T keeps q = l31 lane-local.
#define SWZV(d) (((((d) & 7) ^ (((d) >> 3) & 7))) << 4)

__global__ __launch_bounds__(256, 2) void attn_kernel(
    const unsigned short* __restrict__ Q,   // [4096][2048] (roped)
    const unsigned short* __restrict__ Kc,  // [B][2048][256]
    const unsigned short* __restrict__ Vc,  // [B][2048][256]
    unsigned short* __restrict__ Ctx) {     // [4096][2048]
  __shared__ unsigned short Ks[64 * 256];   // 32KB, row 512B, swizzled, kv-bitswapped
  __shared__ unsigned short Vt[256 * 64];   // 32KB, [d][kv], swizzled
  const int tid = threadIdx.x;
  const int lane = tid & 63, wid = tid >> 6;
  const int l31 = lane & 31, hi = lane >> 5;
  const int qt = blockIdx.x, h = blockIdx.y, b = blockIdx.z;

  // Q fragments (B operand of QK^T): lane holds Q[q=qrow][d = kc*16 + hi*8 + j]
  const size_t qrow = (size_t)(b * L_ + qt * 128 + wid * 32 + l31);
  const unsigned short* qp = Q + qrow * 2048 + h * 256 + hi * 8;
  s16x8 qf[16];
#pragma unroll
  for (int kc = 0; kc < 16; ++kc) qf[kc] = *(const s16x8*)(qp + kc * 16);

  f32x16 oacc[8];   // O^T: oacc[dg][r] = O[q=l31][d = dg*32 + (r&3)+8*(r>>2)+4hi]
#pragma unroll
  for (int dg = 0; dg < 8; ++dg)
#pragma unroll
    for (int r = 0; r < 16; ++r) oacc[dg][r] = 0.f;
  float m_run = -__builtin_inff(), l_run = 0.f;

  const unsigned short* Kb = Kc + (size_t)b * LC_ * 256;
  const unsigned short* Vb = Vc + (size_t)b * LC_ * 256;

  for (int kt = 0; kt < LC_ / 64; ++kt) {
    __syncthreads();
    // stage K: dest row rr holds K[kv = rr with bits 2<->3 swapped]
#pragma unroll
    for (int i = 0; i < 8; ++i) {
      int Li = i * 4096 + tid * 16;
      int row = Li >> 9;
      int kvp = (row & ~12) | ((row & 4) << 1) | ((row & 8) >> 1);
      int kb = (Li & 511) ^ ((row & 7) << 4);
      GLL16((const char*)(Kb + (size_t)(kt * 64 + kvp) * 256) + kb, (char*)Ks + Li);
    }
    // stage V transposed (Vt[d][kv], b32 pair writes; R7-verified pattern)
#pragma unroll
    for (int p = 0; p < 4; ++p) {
      int id = p * 256 + tid;
      int dgrp = id & 31, kvp2 = id >> 5;
      int d0 = dgrp * 8, kv0 = kvp2 * 2;
      const unsigned short* v0p = Vb + (size_t)(kt * 64 + kv0) * 256 + d0;
      s16x8 r0 = *(const s16x8*)v0p;
      s16x8 r1 = *(const s16x8*)(v0p + 256);
#pragma unroll
      for (int j = 0; j < 8; ++j) {
        int d = d0 + j;
        unsigned int val = (unsigned int)(unsigned short)r0[j] |
                           ((unsigned int)(unsigned short)r1[j] << 16);
        *(unsigned int*)((char*)Vt + d * 128 + ((kv0 * 2) ^ SWZV(d))) = val;
      }
    }
    __syncthreads();

    // S^T = K * Q^T: two 32x32 tiles (kv'-halves); A = K rows, B = qf
    f32x16 s0, s1;
#pragma unroll
    for (int r = 0; r < 16; ++r) { s0[r] = 0.f; s1[r] = 0.f; }
#pragma unroll
    for (int kc = 0; kc < 16; ++kc) {
      int ko = kc * 32 + hi * 16;
      int r0 = l31, r1 = 32 + l31;
      s16x8 kf0 = *(const s16x8*)((const char*)Ks + r0 * 512 + (ko ^ ((r0 & 7) << 4)));
      s16x8 kf1 = *(const s16x8*)((const char*)Ks + r1 * 512 + (ko ^ ((r1 & 7) << 4)));
      s0 = __builtin_amdgcn_mfma_f32_32x32x16_bf16(kf0, qf[kc], s0, 0, 0, 0);
      s1 = __builtin_amdgcn_mfma_f32_32x32x16_bf16(kf1, qf[kc], s1, 0, 0, 0);
    }

    // online softmax; q = l31 lane-local; lane + partner(l^32) cover 64 kv
    float sv0[16], sv1[16];
    float mt = -__builtin_inff();
#pragma unroll
    for (int r = 0; r < 16; ++r) {
      sv0[r] = s0[r] * 0.0625f;
      sv1[r] = s1[r] * 0.0625f;
      mt = fmaxf(mt, fmaxf(sv0[r], sv1[r]));
    }
    mt = fmaxf(mt, __shfl_xor(mt, 32));
    if (!__all(mt <= m_run + 8.0f)) {
      float mnew = fmaxf(m_run, mt);
      float alpha = __expf(m_run - mnew);   // lane-local (O^T col = q = l31)
#pragma unroll
      for (int dg = 0; dg < 8; ++dg)
#pragma unroll
        for (int r = 0; r < 16; ++r) oacc[dg][r] *= alpha;
      l_run *= alpha;
      m_run = mnew;
    }
    float rs = 0.f;
#pragma unroll
    for (int r = 0; r < 16; ++r) {
      sv0[r] = __expf(sv0[r] - m_run);
      sv1[r] = __expf(sv1[r] - m_run);
      rs += sv0[r] + sv1[r];
    }
    rs += __shfl_xor(rs, 32);
    l_run += rs;

    // pack P: w[mi*8+rr] = (sv[2rr], sv[2rr+1]); B-frag slice s = w[4s..4s+3]
    unsigned int pk[16];
#pragma unroll
    for (int rr = 0; rr < 8; ++rr) {
      pk[rr]     = (unsigned int)f2b(sv0[2 * rr]) | ((unsigned int)f2b(sv0[2 * rr + 1]) << 16);
      pk[8 + rr] = (unsigned int)f2b(sv1[2 * rr]) | ((unsigned int)f2b(sv1[2 * rr + 1]) << 16);
    }

    // PV: O^T += V^T-frag * P^T-frag; zero cross-lane ops
#pragma unroll
    for (int s = 0; s < 4; ++s) {
      union { unsigned int u[4]; s16x8 v; } pf;
      pf.u[0] = pk[4 * s]; pf.u[1] = pk[4 * s + 1];
      pf.u[2] = pk[4 * s + 2]; pf.u[3] = pk[4 * s + 3];
      int ko = s * 32 + hi * 16;
#pragma unroll
      for (int dg = 0; dg < 8; ++dg) {
        int d = dg * 32 + l31;
        s16x8 vf = *(const s16x8*)((const char*)Vt + d * 128 + (ko ^ SWZV(d)));
        oacc[dg] = __builtin_amdgcn_mfma_f32_32x32x16_bf16(vf, pf.v, oacc[dg], 0, 0, 0);
      }
    }
  }

  // store: O[q][d], d = dg*32 + rq*8 + hi*4 + (0..3); b64 per group; lane-local
  float lf = 1.0f / l_run;
  const size_t obase = qrow * 2048 + h * 256;
#pragma unroll
  for (int dg = 0; dg < 8; ++dg)
#pragma unroll
    for (int rq = 0; rq < 4; ++rq) {
      int d = dg * 32 + rq * 8 + hi * 4;
      u16x4 o = { f2b(oacc[dg][rq * 4 + 0] * lf), f2b(oacc[dg][rq * 4 + 1] * lf),
                  f2b(oacc[dg][rq * 4 + 2] * lf), f2b(oacc[dg][rq * 4 + 3] * lf) };
      *(u16x4*)(Ctx + obase + d) = o;
    }
}

// ---------------------------------------------------------------- launch
extern "C" void kernel_launch(void* const* d_in, const int* in_sizes, int n_in,
                              void* d_out, int out_size, void* d_ws, size_t ws_size,
                              hipStream_t stream) {
  const float* x   = (const float*)d_in[0];
  const float* tk  = (const float*)d_in[1];
  const float* tv  = (const float*)d_in[2];
  const float* ln1 = (const float*)d_in[3];
  const float* ln2 = (const float*)d_in[4];
  const float* Wq  = (const float*)d_in[5];
  const float* Wk  = (const float*)d_in[6];
  const float* Wv  = (const float*)d_in[7];
  const float* Wo  = (const float*)d_in[8];
  const float* Wg  = (const float*)d_in[9];
  const float* Wu  = (const float*)d_in[10];
  const float* Wd  = (const float*)d_in[11];
  float* out = (float*)d_out;
  char* ws = (char*)d_ws;

  (void)hipFuncSetAttribute((const void*)gemm256<0>,
                            hipFuncAttributeMaxDynamicSharedMemorySize, 131072);
  (void)hipFuncSetAttribute((const void*)gemm256<1>,
                            hipFuncAttributeMaxDynamicSharedMemorySize, 131072);

  // workspace layout (126.1 MB, lifetime-based aliasing)
  unsigned short* tk_bf  = (unsigned short*)(ws + 0);
  unsigned short* tv_bf  = (unsigned short*)(ws + 8388608);
  unsigned short* k_bf   = (unsigned short*)(ws + 16777216);
  unsigned short* v_bf   = (unsigned short*)(ws + 25165824);
  unsigned short* g_bf   = (unsigned short*)(ws + 0);         // FFN gate (tk/tv dead)
  unsigned short* q_bf   = (unsigned short*)(ws + 33554432);
  unsigned short* ctx_bf = (unsigned short*)(ws + 50331648);
  unsigned short* u_bf   = (unsigned short*)(ws + 33554432);  // aliases q (dead)
  unsigned short* wq_bf  = (unsigned short*)(ws + 67108864);
  unsigned short* wk_bf  = (unsigned short*)(ws + 71303168);
  unsigned short* wv_bf  = (unsigned short*)(ws + 71434240);
  unsigned short* wo_bf  = (unsigned short*)(ws + 71565312);
  unsigned short* wg_bf  = (unsigned short*)(ws + 75759616);
  unsigned short* wu_bf  = (unsigned short*)(ws + 84148224);
  unsigned short* wd_bf  = (unsigned short*)(ws + 92536832);
  unsigned short* h_bf   = (unsigned short*)(ws + 100925440);
  float*          x2     = (float*)(ws + 109314048);

  dim3 blk(256);
  convert9<<<dim3(24704), blk, 0, stream>>>(
      Wq, Wk, Wv, Wo, Wg, Wu, Wd, tk, tv,
      wq_bf, wk_bf, wv_bf, wo_bf, wg_bf, wu_bf, wd_bf, tk_bf, tv_bf);

  rmsnorm_kernel<<<dim3(4096), blk, 0, stream>>>(x, ln1, h_bf);
  gemm_nt<0, 1><<<dim3(16, 32), blk, 0, stream>>>(h_bf, wq_bf, nullptr, q_bf, 4096, 2048, 1024);
  rope_kernel<<<dim3(16384), blk, 0, stream>>>(q_bf);
  gemm_nt64<0, 1><<<dim3(2, 256), blk, 0, stream>>>(tk_bf, wk_bf, nullptr, k_bf, 16384, 256, 256);
  gemm_nt64<0, 1><<<dim3(2, 256), blk, 0, stream>>>(tv_bf, wv_bf, nullptr, v_bf, 16384, 256, 256);
  attn_kernel<<<dim3(4, 8, 8), dim3(256), 0, stream>>>(q_bf, k_bf, v_bf, ctx_bf);
  gemm_nt64<1, 0><<<dim3(8, 64), blk, 0, stream>>>(ctx_bf, wo_bf, x, x2, 4096, 1024, 2048);
  rmsnorm_kernel<<<dim3(4096), blk, 0, stream>>>(x2, ln2, h_bf);
  gemm256<0><<<dim3(16, 16), dim3(512), 131072, stream>>>(h_bf, wg_bf, nullptr, g_bf, 4096, 4096, 1024);
  gemm256<1><<<dim3(16, 16), dim3(512), 131072, stream>>>(h_bf, wu_bf, g_bf, g_bf, 4096, 4096, 1024);
  gemm_nt64<1, 0><<<dim3(8, 64), blk, 0, stream>>>(g_bf, wd_bf, x2, out, 4096, 1024, 4096);
}

// Round 14
// 401.761 us; speedup vs baseline: 1.8148x; 1.8148x over previous
//
#include <hip/hip_runtime.h>

typedef __attribute__((ext_vector_type(4))) float f32x4;
typedef __attribute__((ext_vector_type(16))) float f32x16;
typedef __attribute__((ext_vector_type(8))) short s16x8;
typedef __attribute__((ext_vector_type(4))) unsigned short u16x4;

#define B_    8
#define L_    512
#define LC_   2048
#define EMBD  1024

__device__ __forceinline__ float b2f(unsigned short u) {
  unsigned int i = ((unsigned int)u) << 16;
  float f; __builtin_memcpy(&f, &i, 4); return f;
}
__device__ __forceinline__ unsigned short f2b(float f) {
  unsigned int i; __builtin_memcpy(&i, &f, 4);
  unsigned int r = i + 0x7FFFu + ((i >> 16) & 1u);
  return (unsigned short)(r >> 16);
}

#define GLL16(g, l)                                                         \
  __builtin_amdgcn_global_load_lds(                                         \
      (__attribute__((address_space(1))) void*)(g),                         \
      (__attribute__((address_space(3))) void*)(l), 16, 0, 0)

#define VMCNT6() asm volatile("s_waitcnt vmcnt(6)" ::: "memory")
#define VMCNT0() asm volatile("s_waitcnt vmcnt(0)" ::: "memory")
#define LGKM0()  asm volatile("s_waitcnt lgkmcnt(0)" ::: "memory")

// ---------------------------------------------------------------- converts (all 9 in one launch)
__global__ __launch_bounds__(256) void convert9(
    const float* s0, const float* s1, const float* s2, const float* s3,
    const float* s4, const float* s5, const float* s6, const float* s7,
    const float* s8,
    unsigned short* d0, unsigned short* d1, unsigned short* d2,
    unsigned short* d3, unsigned short* d4, unsigned short* d5,
    unsigned short* d6, unsigned short* d7, unsigned short* d8) {
  int bk = blockIdx.x;
  const float* s; unsigned short* d; int base;
  if      (bk <  2048) { s = s0; d = d0; base = 0; }
  else if (bk <  2112) { s = s1; d = d1; base = 2048; }
  else if (bk <  2176) { s = s2; d = d2; base = 2112; }
  else if (bk <  4224) { s = s3; d = d3; base = 2176; }
  else if (bk <  8320) { s = s4; d = d4; base = 4224; }
  else if (bk < 12416) { s = s5; d = d5; base = 8320; }
  else if (bk < 16512) { s = s6; d = d6; base = 12416; }
  else if (bk < 20608) { s = s7; d = d7; base = 16512; }
  else                 { s = s8; d = d8; base = 20608; }
  int i = (bk - base) * 256 + threadIdx.x;
  float4 v = ((const float4*)s)[i];
  u16x4 o = { f2b(v.x), f2b(v.y), f2b(v.z), f2b(v.w) };
  ((u16x4*)d)[i] = o;
}

// ---------------------------------------------------------------- rmsnorm
__global__ __launch_bounds__(256) void rmsnorm_kernel(
    const float* __restrict__ x, const float* __restrict__ w,
    unsigned short* __restrict__ out) {
  int row = blockIdx.x;
  int tid = threadIdx.x;
  float4 v = ((const float4*)(x + (size_t)row * EMBD))[tid];
  float ss = v.x*v.x + v.y*v.y + v.z*v.z + v.w*v.w;
#pragma unroll
  for (int o = 1; o < 64; o <<= 1) ss += __shfl_xor(ss, o);
  __shared__ float red[4];
  if ((tid & 63) == 0) red[tid >> 6] = ss;
  __syncthreads();
  float tot = red[0] + red[1] + red[2] + red[3];
  float rs = rsqrtf(tot * (1.0f / EMBD) + 1.1920928955078125e-07f);
  float4 wv = ((const float4*)w)[tid];
  u16x4 o = { f2b(v.x*rs*wv.x), f2b(v.y*rs*wv.y), f2b(v.z*rs*wv.z), f2b(v.w*rs*wv.w) };
  ((u16x4*)(out + (size_t)row * EMBD))[tid] = o;
}

// ---------------------------------------------------------------- rope (in-place on [4096][2048] bf16)
__global__ __launch_bounds__(256) void rope_kernel(unsigned short* __restrict__ q) {
  int idx = blockIdx.x * 256 + threadIdx.x;
  int i   = idx & 127;
  int h   = (idx >> 7) & 7;
  int row = idx >> 10;
  int l   = row & (L_ - 1);
  size_t base = (size_t)row * 2048 + h * 256 + i;
  float x1 = b2f(q[base]);
  float x2 = b2f(q[base + 128]);
  float ts  = powf(10000.0f, (float)i * (2.0f / 256.0f));
  float rad = (float)l / ts;
  float s, c;
  sincosf(rad, &s, &c);
  q[base]       = f2b(x1 * c - x2 * s);
  q[base + 128] = f2b(x2 * c + x1 * s);
}

// ---------------------------------------------------------------- NT GEMM 128x128 (2-barrier)
template <int ADD_RES, int OUT_BF16>
__global__ __launch_bounds__(256, 2) void gemm_nt(
    const unsigned short* __restrict__ A, const unsigned short* __restrict__ Bw,
    const float* __restrict__ Res, void* __restrict__ C, int M, int N, int K) {
  __shared__ unsigned short As[128 * 64];
  __shared__ unsigned short Bs[128 * 64];
  const int tid = threadIdx.x;
  const int lane = tid & 63, wid = tid >> 6;
  const int l15 = lane & 15, l4 = lane >> 4;
  const int wr = wid >> 1, wc = wid & 1;
  const int m0 = blockIdx.y * 128, n0 = blockIdx.x * 128;

  const f32x4 fz = {0.f, 0.f, 0.f, 0.f};
  f32x4 acc[4][4];
#pragma unroll
  for (int i = 0; i < 4; ++i)
#pragma unroll
    for (int j = 0; j < 4; ++j) acc[i][j] = fz;

  for (int k0 = 0; k0 < K; k0 += 64) {
    __syncthreads();
#pragma unroll
    for (int i = 0; i < 4; ++i) {
      int Li = i * 4096 + tid * 16;
      int row = Li >> 7;
      int kb = (Li & 127) ^ ((row & 7) << 4);
      GLL16((const char*)(A + (size_t)(m0 + row) * K + k0) + kb, (char*)As + Li);
      GLL16((const char*)(Bw + (size_t)(n0 + row) * K + k0) + kb, (char*)Bs + Li);
    }
    __syncthreads();
#pragma unroll
    for (int kk = 0; kk < 2; ++kk) {
      s16x8 af[4], bfr[4];
#pragma unroll
      for (int mi = 0; mi < 4; ++mi) {
        int row = wr * 64 + mi * 16 + l15;
        int kb = (kk * 64 + l4 * 16) ^ ((row & 7) << 4);
        af[mi] = *(const s16x8*)((const char*)As + row * 128 + kb);
      }
#pragma unroll
      for (int ni = 0; ni < 4; ++ni) {
        int row = wc * 64 + ni * 16 + l15;
        int kb = (kk * 64 + l4 * 16) ^ ((row & 7) << 4);
        bfr[ni] = *(const s16x8*)((const char*)Bs + row * 128 + kb);
      }
#pragma unroll
      for (int mi = 0; mi < 4; ++mi)
#pragma unroll
        for (int ni = 0; ni < 4; ++ni)
          acc[mi][ni] = __builtin_amdgcn_mfma_f32_16x16x32_bf16(
              af[mi], bfr[ni], acc[mi][ni], 0, 0, 0);
    }
  }
#pragma unroll
  for (int mi = 0; mi < 4; ++mi) {
#pragma unroll
    for (int r = 0; r < 4; ++r) {
      int grow = m0 + wr * 64 + mi * 16 + l4 * 4 + r;
      size_t base = (size_t)grow * N + n0 + wc * 64 + l15;
#pragma unroll
      for (int ni = 0; ni < 4; ++ni) {
        float v = acc[mi][ni][r];
        size_t idx = base + ni * 16;
        if (ADD_RES) v += Res[idx];
        if (OUT_BF16) ((unsigned short*)C)[idx] = f2b(v);
        else          ((float*)C)[idx] = v;
      }
    }
  }
}

// ---------------------------------------------------------------- NT GEMM 64x128 (512-block grids, 2/CU)
template <int ADD_RES, int OUT_BF16>
__global__ __launch_bounds__(256, 2) void gemm_nt64(
    const unsigned short* __restrict__ A, const unsigned short* __restrict__ Bw,
    const float* __restrict__ Res, void* __restrict__ C, int M, int N, int K) {
  __shared__ unsigned short As[64 * 64];
  __shared__ unsigned short Bs[128 * 64];
  const int tid = threadIdx.x;
  const int lane = tid & 63, wid = tid >> 6;
  const int l15 = lane & 15, l4 = lane >> 4;
  const int wr = wid >> 1, wc = wid & 1;
  const int m0 = blockIdx.y * 64, n0 = blockIdx.x * 128;

  const f32x4 fz = {0.f, 0.f, 0.f, 0.f};
  f32x4 acc[2][4];
#pragma unroll
  for (int i = 0; i < 2; ++i)
#pragma unroll
    for (int j = 0; j < 4; ++j) acc[i][j] = fz;

  for (int k0 = 0; k0 < K; k0 += 64) {
    __syncthreads();
#pragma unroll
    for (int i = 0; i < 2; ++i) {
      int Li = i * 4096 + tid * 16;
      int row = Li >> 7;
      int kb = (Li & 127) ^ ((row & 7) << 4);
      GLL16((const char*)(A + (size_t)(m0 + row) * K + k0) + kb, (char*)As + Li);
    }
#pragma unroll
    for (int i = 0; i < 4; ++i) {
      int Li = i * 4096 + tid * 16;
      int row = Li >> 7;
      int kb = (Li & 127) ^ ((row & 7) << 4);
      GLL16((const char*)(Bw + (size_t)(n0 + row) * K + k0) + kb, (char*)Bs + Li);
    }
    __syncthreads();
#pragma unroll
    for (int kk = 0; kk < 2; ++kk) {
      s16x8 af[2], bfr[4];
#pragma unroll
      for (int mi = 0; mi < 2; ++mi) {
        int row = wr * 32 + mi * 16 + l15;
        int kb = (kk * 64 + l4 * 16) ^ ((row & 7) << 4);
        af[mi] = *(const s16x8*)((const char*)As + row * 128 + kb);
      }
#pragma unroll
      for (int ni = 0; ni < 4; ++ni) {
        int row = wc * 64 + ni * 16 + l15;
        int kb = (kk * 64 + l4 * 16) ^ ((row & 7) << 4);
        bfr[ni] = *(const s16x8*)((const char*)Bs + row * 128 + kb);
      }
#pragma unroll
      for (int mi = 0; mi < 2; ++mi)
#pragma unroll
        for (int ni = 0; ni < 4; ++ni)
          acc[mi][ni] = __builtin_amdgcn_mfma_f32_16x16x32_bf16(
              af[mi], bfr[ni], acc[mi][ni], 0, 0, 0);
    }
  }
#pragma unroll
  for (int mi = 0; mi < 2; ++mi) {
#pragma unroll
    for (int r = 0; r < 4; ++r) {
      int grow = m0 + wr * 32 + mi * 16 + l4 * 4 + r;
      size_t base = (size_t)grow * N + n0 + wc * 64 + l15;
#pragma unroll
      for (int ni = 0; ni < 4; ++ni) {
        float v = acc[mi][ni][r];
        size_t idx = base + ni * 16;
        if (ADD_RES) v += Res[idx];
        if (OUT_BF16) ((unsigned short*)C)[idx] = f2b(v);
        else          ((float*)C)[idx] = v;
      }
    }
  }
}

// ---------------------------------------------------------------- 256x256 8-phase GEMM (T1..T5; optional fused silu(g)*acc)
template <int SWIGLU>
__global__ __launch_bounds__(512, 2) void gemm256(
    const unsigned short* __restrict__ A, const unsigned short* __restrict__ Bw,
    const unsigned short* __restrict__ G, unsigned short* __restrict__ C,
    int M, int N, int K) {
  extern __shared__ char smem[];
  const int tid = threadIdx.x;
  const int lane = tid & 63;
  const int wid = tid >> 6;
  const int wr = wid >> 2, wc = wid & 3;
  const int l15 = lane & 15, g = lane >> 4;
  int flat = blockIdx.y * 16 + blockIdx.x;
  flat = (flat & 7) * 32 + (flat >> 3);
  const int m0 = (flat >> 4) * 256, n0 = (flat & 15) * 256;
  const int T = K >> 6;
  const int swz = (l15 & 7) << 4;

  auto stage = [&](int t, int mat, int half) {
    char* dst = smem + mat * 65536 + (t & 1) * 32768 + half * 16384;
    const unsigned short* src = (mat ? Bw + (size_t)(n0 + half * 128) * K
                                     : A + (size_t)(m0 + half * 128) * K) + t * 64;
#pragma unroll
    for (int i = 0; i < 2; ++i) {
      int Li = i * 8192 + tid * 16;
      int row = Li >> 7;
      int kb = (Li & 127) ^ ((row & 7) << 4);
      GLL16((const char*)(src + (size_t)row * K) + kb, dst + Li);
    }
  };

  const f32x4 fz = {0.f, 0.f, 0.f, 0.f};
  f32x4 acc[2][2][4][2];
#pragma unroll
  for (int ms = 0; ms < 2; ++ms)
#pragma unroll
    for (int ns = 0; ns < 2; ++ns)
#pragma unroll
      for (int mi = 0; mi < 4; ++mi)
#pragma unroll
        for (int ni = 0; ni < 2; ++ni) acc[ms][ns][mi][ni] = fz;

  stage(0, 1, 0); stage(0, 1, 1); stage(0, 0, 0); stage(0, 0, 1);
  stage(1, 1, 0); stage(1, 1, 1); stage(1, 0, 0);
  VMCNT6();
  __builtin_amdgcn_s_barrier();

  for (int t = 0; t < T; ++t) {
    char* Ab = smem + (t & 1) * 32768 + wr * 16384;
    char* Bb = smem + 65536 + (t & 1) * 32768 + (wc >> 1) * 16384;
    const int bn = (wc & 1) * 64;
    s16x8 a[4][2], b0[2][2], b1[2][2];

#pragma unroll
    for (int mi = 0; mi < 4; ++mi) {
      int row = mi * 16 + l15;
#pragma unroll
      for (int kk = 0; kk < 2; ++kk)
        a[mi][kk] = *(const s16x8*)(Ab + row * 128 + ((kk * 64 + g * 16) ^ swz));
    }
#pragma unroll
    for (int ni = 0; ni < 2; ++ni) {
      int r0 = (bn + ni * 16 + l15) * 128;
      int r1 = (bn + 32 + ni * 16 + l15) * 128;
#pragma unroll
      for (int kk = 0; kk < 2; ++kk) {
        int ko = (kk * 64 + g * 16) ^ swz;
        b0[ni][kk] = *(const s16x8*)(Bb + r0 + ko);
        b1[ni][kk] = *(const s16x8*)(Bb + r1 + ko);
      }
    }
    if (t + 1 < T) stage(t + 1, 0, 1);
    __builtin_amdgcn_s_barrier();
    LGKM0();
    __builtin_amdgcn_sched_barrier(0);
    __builtin_amdgcn_s_setprio(1);
#pragma unroll
    for (int mi = 0; mi < 4; ++mi)
#pragma unroll
      for (int ni = 0; ni < 2; ++ni)
#pragma unroll
        for (int kk = 0; kk < 2; ++kk)
          acc[0][0][mi][ni] = __builtin_amdgcn_mfma_f32_16x16x32_bf16(
              a[mi][kk], b0[ni][kk], acc[0][0][mi][ni], 0, 0, 0);
    __builtin_amdgcn_s_setprio(0);
    __builtin_amdgcn_s_barrier();

    if (t + 2 < T) stage(t + 2, 1, 0);
    __builtin_amdgcn_s_barrier();
    __builtin_amdgcn_s_setprio(1);
#pragma unroll
    for (int mi = 0; mi < 4; ++mi)
#pragma unroll
      for (int ni = 0; ni < 2; ++ni)
#pragma unroll
        for (int kk = 0; kk < 2; ++kk)
          acc[0][1][mi][ni] = __builtin_amdgcn_mfma_f32_16x16x32_bf16(
              a[mi][kk], b1[ni][kk], acc[0][1][mi][ni], 0, 0, 0);
    __builtin_amdgcn_s_setprio(0);
    __builtin_amdgcn_s_barrier();

#pragma unroll
    for (int mi = 0; mi < 4; ++mi) {
      int row = 64 + mi * 16 + l15;
#pragma unroll
      for (int kk = 0; kk < 2; ++kk)
        a[mi][kk] = *(const s16x8*)(Ab + row * 128 + ((kk * 64 + g * 16) ^ swz));
    }
    if (t + 2 < T) stage(t + 2, 1, 1);
    __builtin_amdgcn_s_barrier();
    LGKM0();
    __builtin_amdgcn_sched_barrier(0);
    __builtin_amdgcn_s_setprio(1);
#pragma unroll
    for (int mi = 0; mi < 4; ++mi)
#pragma unroll
      for (int ni = 0; ni < 2; ++ni)
#pragma unroll
        for (int kk = 0; kk < 2; ++kk)
          acc[1][0][mi][ni] = __builtin_amdgcn_mfma_f32_16x16x32_bf16(
              a[mi][kk], b0[ni][kk], acc[1][0][mi][ni], 0, 0, 0);
    __builtin_amdgcn_s_setprio(0);
    __builtin_amdgcn_s_barrier();

    if (t + 2 < T) { stage(t + 2, 0, 0); VMCNT6(); }
    else           { VMCNT0(); }
    __builtin_amdgcn_s_barrier();
    __builtin_amdgcn_s_setprio(1);
#pragma unroll
    for (int mi = 0; mi < 4; ++mi)
#pragma unroll
      for (int ni = 0; ni < 2; ++ni)
#pragma unroll
        for (int kk = 0; kk < 2; ++kk)
          acc[1][1][mi][ni] = __builtin_amdgcn_mfma_f32_16x16x32_bf16(
              a[mi][kk], b1[ni][kk], acc[1][1][mi][ni], 0, 0, 0);
    __builtin_amdgcn_s_setprio(0);
    __builtin_amdgcn_s_barrier();
  }

#pragma unroll
  for (int ms = 0; ms < 2; ++ms)
#pragma unroll
    for (int mi = 0; mi < 4; ++mi)
#pragma unroll
      for (int r = 0; r < 4; ++r) {
        int grow = m0 + wr * 128 + ms * 64 + mi * 16 + g * 4 + r;
        size_t base = (size_t)grow * N + n0 + wc * 64;
#pragma unroll
        for (int ns = 0; ns < 2; ++ns)
#pragma unroll
          for (int ni = 0; ni < 2; ++ni) {
            size_t idx = base + ns * 32 + ni * 16 + l15;
            float v = acc[ms][ns][mi][ni][r];
            if (SWIGLU) {
              float gf = b2f(G[idx]);
              v *= gf / (1.0f + __expf(-gf));
            }
            C[idx] = f2b(v);
          }
      }
}

// ---------------------------------------------------------------- fused attention (32x32x16, O^T, zero-shuffle, LDS dbuf)
// grid (qt=4, h=8, b=8) = 256 blocks, 256 thr = 4 waves x 32 q-rows; 32 KV
// tiles/block; 1 wave/SIMD (total regs ~372+32 of 512, no spill). Since there
// is NO cross-block overlap at this occupancy, double-buffer LDS and split
// staging (T14): issue K GLL16s + V global loads for t+1 BEFORE compute(t);
// vmcnt(0) + V-write after; ONE barrier per tile (was 2). K staged with kv
// bits 2<->3 swapped so packed S^T values form PV B-frags; O^T lane-local.
#define SWZV(d) (((((d) & 7) ^ (((d) >> 3) & 7))) << 4)

__global__ __launch_bounds__(256, 1) void attn_kernel(
    const unsigned short* __restrict__ Q,   // [4096][2048] (roped)
    const unsigned short* __restrict__ Kc,  // [B][2048][256]
    const unsigned short* __restrict__ Vc,  // [B][2048][256]
    unsigned short* __restrict__ Ctx) {     // [4096][2048]
  extern __shared__ char ats[];   // Ks[2] 2x32KB | Vt[2] 2x32KB = 128KB
  const int tid = threadIdx.x;
  const int lane = tid & 63, wid = tid >> 6;
  const int l31 = lane & 31, hi = lane >> 5;
  const int qt = blockIdx.x, h = blockIdx.y, b = blockIdx.z;

  // Q fragments (B operand of QK^T): lane holds Q[q=qrow][d = kc*16 + hi*8 + j]
  const size_t qrow = (size_t)(b * L_ + qt * 128 + wid * 32 + l31);
  const unsigned short* qp = Q + qrow * 2048 + h * 256 + hi * 8;
  s16x8 qf[16];
#pragma unroll
  for (int kc = 0; kc < 16; ++kc) qf[kc] = *(const s16x8*)(qp + kc * 16);

  f32x16 oacc[8];   // O^T: oacc[dg][r] = O[q=l31][d = dg*32 + (r&3)+8*(r>>2)+4hi]
#pragma unroll
  for (int dg = 0; dg < 8; ++dg)
#pragma unroll
    for (int r = 0; r < 16; ++r) oacc[dg][r] = 0.f;
  float m_run = -__builtin_inff(), l_run = 0.f;

  const unsigned short* Kb = Kc + (size_t)b * LC_ * 256;
  const unsigned short* Vb = Vc + (size_t)b * LC_ * 256;

  const int dgrp = tid & 31, kvq = tid >> 5;   // V-staging coords (all 256 thr)
  s16x8 vr[4][2];

  auto stageK = [&](int kt, char* dstK) {
#pragma unroll
    for (int i = 0; i < 8; ++i) {
      int Li = i * 4096 + tid * 16;
      int row = Li >> 9;
      int kvp = (row & ~12) | ((row & 4) << 1) | ((row & 8) >> 1);
      int kb = (Li & 511) ^ ((row & 7) << 4);
      GLL16((const char*)(Kb + (size_t)(kt * 64 + kvp) * 256) + kb, dstK + Li);
    }
  };
  auto loadV = [&](int kt) {
#pragma unroll
    for (int p = 0; p < 4; ++p) {
      int kv0 = (p * 8 + kvq) * 2;
      const unsigned short* v0p = Vb + (size_t)(kt * 64 + kv0) * 256 + dgrp * 8;
      vr[p][0] = *(const s16x8*)v0p;
      vr[p][1] = *(const s16x8*)(v0p + 256);
    }
  };
  auto writeV = [&](char* dstV) {
#pragma unroll
    for (int p = 0; p < 4; ++p) {
      int d0 = dgrp * 8, kv0 = (p * 8 + kvq) * 2;
#pragma unroll
      for (int j = 0; j < 8; ++j) {
        int d = d0 + j;
        unsigned int val = (unsigned int)(unsigned short)vr[p][0][j] |
                           ((unsigned int)(unsigned short)vr[p][1][j] << 16);
        *(unsigned int*)(dstV + d * 128 + ((kv0 * 2) ^ SWZV(d))) = val;
      }
    }
  };

  // prologue: stage tile 0 into buffer 0
  stageK(0, ats);
  loadV(0);
  VMCNT0();
  writeV(ats + 65536);
  __syncthreads();

  for (int kt = 0; kt < LC_ / 64; ++kt) {
    const int cur = kt & 1, nxt = cur ^ 1;
    char* KsB = ats + cur * 32768;
    char* VtB = ats + 65536 + cur * 32768;
    const bool more = (kt + 1 < LC_ / 64);
    if (more) { stageK(kt + 1, ats + nxt * 32768); loadV(kt + 1); }

    // S^T = K * Q^T: two 32x32 tiles (kv'-halves); A = K rows, B = qf
    f32x16 s0, s1;
#pragma unroll
    for (int r = 0; r < 16; ++r) { s0[r] = 0.f; s1[r] = 0.f; }
#pragma unroll
    for (int kc = 0; kc < 16; ++kc) {
      int ko = kc * 32 + hi * 16;
      int r0 = l31, r1 = 32 + l31;
      s16x8 kf0 = *(const s16x8*)(KsB + r0 * 512 + (ko ^ ((r0 & 7) << 4)));
      s16x8 kf1 = *(const s16x8*)(KsB + r1 * 512 + (ko ^ ((r1 & 7) << 4)));
      s0 = __builtin_amdgcn_mfma_f32_32x32x16_bf16(kf0, qf[kc], s0, 0, 0, 0);
      s1 = __builtin_amdgcn_mfma_f32_32x32x16_bf16(kf1, qf[kc], s1, 0, 0, 0);
    }

    // online softmax; q = l31 lane-local; lane + partner(l^32) cover 64 kv
    float sv0[16], sv1[16];
    float mt = -__builtin_inff();
#pragma unroll
    for (int r = 0; r < 16; ++r) {
      sv0[r] = s0[r] * 0.0625f;
      sv1[r] = s1[r] * 0.0625f;
      mt = fmaxf(mt, fmaxf(sv0[r], sv1[r]));
    }
    mt = fmaxf(mt, __shfl_xor(mt, 32));
    if (!__all(mt <= m_run + 8.0f)) {
      float mnew = fmaxf(m_run, mt);
      float alpha = __expf(m_run - mnew);   // lane-local (O^T col = q = l31)
#pragma unroll
      for (int dg = 0; dg < 8; ++dg)
#pragma unroll
        for (int r = 0; r < 16; ++r) oacc[dg][r] *= alpha;
      l_run *= alpha;
      m_run = mnew;
    }
    float rs = 0.f;
#pragma unroll
    for (int r = 0; r < 16; ++r) {
      sv0[r] = __expf(sv0[r] - m_run);
      sv1[r] = __expf(sv1[r] - m_run);
      rs += sv0[r] + sv1[r];
    }
    rs += __shfl_xor(rs, 32);
    l_run += rs;

    // pack P: w[mi*8+rr] = (sv[2rr], sv[2rr+1]); B-frag slice s = w[4s..4s+3]
    unsigned int pk[16];
#pragma unroll
    for (int rr = 0; rr < 8; ++rr) {
      pk[rr]     = (unsigned int)f2b(sv0[2 * rr]) | ((unsigned int)f2b(sv0[2 * rr + 1]) << 16);
      pk[8 + rr] = (unsigned int)f2b(sv1[2 * rr]) | ((unsigned int)f2b(sv1[2 * rr + 1]) << 16);
    }

    // PV: O^T += V^T-frag * P^T-frag; zero cross-lane ops
#pragma unroll
    for (int s = 0; s < 4; ++s) {
      union { unsigned int u[4]; s16x8 v; } pf;
      pf.u[0] = pk[4 * s]; pf.u[1] = pk[4 * s + 1];
      pf.u[2] = pk[4 * s + 2]; pf.u[3] = pk[4 * s + 3];
      int ko = s * 32 + hi * 16;
#pragma unroll
      for (int dg = 0; dg < 8; ++dg) {
        int d = dg * 32 + l31;
        s16x8 vf = *(const s16x8*)(VtB + d * 128 + (ko ^ SWZV(d)));
        oacc[dg] = __builtin_amdgcn_mfma_f32_32x32x16_bf16(vf, pf.v, oacc[dg], 0, 0, 0);
      }
    }

    // late half of async-STAGE: V-write to next buffer; publish barrier
    if (more) { VMCNT0(); writeV(ats + 65536 + nxt * 32768); }
    else      { VMCNT0(); }
    __syncthreads();
  }

  // store: O[q][d], d = dg*32 + rq*8 + hi*4 + (0..3); b64 per group; lane-local
  float lf = 1.0f / l_run;
  const size_t obase = qrow * 2048 + h * 256;
#pragma unroll
  for (int dg = 0; dg < 8; ++dg)
#pragma unroll
    for (int rq = 0; rq < 4; ++rq) {
      int d = dg * 32 + rq * 8 + hi * 4;
      u16x4 o = { f2b(oacc[dg][rq * 4 + 0] * lf), f2b(oacc[dg][rq * 4 + 1] * lf),
                  f2b(oacc[dg][rq * 4 + 2] * lf), f2b(oacc[dg][rq * 4 + 3] * lf) };
      *(u16x4*)(Ctx + obase + d) = o;
    }
}

// ---------------------------------------------------------------- launch
extern "C" void kernel_launch(void* const* d_in, const int* in_sizes, int n_in,
                              void* d_out, int out_size, void* d_ws, size_t ws_size,
                              hipStream_t stream) {
  const float* x   = (const float*)d_in[0];
  const float* tk  = (const float*)d_in[1];
  const float* tv  = (const float*)d_in[2];
  const float* ln1 = (const float*)d_in[3];
  const float* ln2 = (const float*)d_in[4];
  const float* Wq  = (const float*)d_in[5];
  const float* Wk  = (const float*)d_in[6];
  const float* Wv  = (const float*)d_in[7];
  const float* Wo  = (const float*)d_in[8];
  const float* Wg  = (const float*)d_in[9];
  const float* Wu  = (const float*)d_in[10];
  const float* Wd  = (const float*)d_in[11];
  float* out = (float*)d_out;
  char* ws = (char*)d_ws;

  (void)hipFuncSetAttribute((const void*)gemm256<0>,
                            hipFuncAttributeMaxDynamicSharedMemorySize, 131072);
  (void)hipFuncSetAttribute((const void*)gemm256<1>,
                            hipFuncAttributeMaxDynamicSharedMemorySize, 131072);
  (void)hipFuncSetAttribute((const void*)attn_kernel,
                            hipFuncAttributeMaxDynamicSharedMemorySize, 131072);

  // workspace layout (126.1 MB, lifetime-based aliasing)
  unsigned short* tk_bf  = (unsigned short*)(ws + 0);
  unsigned short* tv_bf  = (unsigned short*)(ws + 8388608);
  unsigned short* k_bf   = (unsigned short*)(ws + 16777216);
  unsigned short* v_bf   = (unsigned short*)(ws + 25165824);
  unsigned short* g_bf   = (unsigned short*)(ws + 0);         // FFN gate (tk/tv dead)
  unsigned short* q_bf   = (unsigned short*)(ws + 33554432);
  unsigned short* ctx_bf = (unsigned short*)(ws + 50331648);
  unsigned short* u_bf   = (unsigned short*)(ws + 33554432);  // aliases q (dead)
  unsigned short* wq_bf  = (unsigned short*)(ws + 67108864);
  unsigned short* wk_bf  = (unsigned short*)(ws + 71303168);
  unsigned short* wv_bf  = (unsigned short*)(ws + 71434240);
  unsigned short* wo_bf  = (unsigned short*)(ws + 71565312);
  unsigned short* wg_bf  = (unsigned short*)(ws + 75759616);
  unsigned short* wu_bf  = (unsigned short*)(ws + 84148224);
  unsigned short* wd_bf  = (unsigned short*)(ws + 92536832);
  unsigned short* h_bf   = (unsigned short*)(ws + 100925440);
  float*          x2     = (float*)(ws + 109314048);

  dim3 blk(256);
  convert9<<<dim3(24704), blk, 0, stream>>>(
      Wq, Wk, Wv, Wo, Wg, Wu, Wd, tk, tv,
      wq_bf, wk_bf, wv_bf, wo_bf, wg_bf, wu_bf, wd_bf, tk_bf, tv_bf);

  rmsnorm_kernel<<<dim3(4096), blk, 0, stream>>>(x, ln1, h_bf);
  gemm_nt<0, 1><<<dim3(16, 32), blk, 0, stream>>>(h_bf, wq_bf, nullptr, q_bf, 4096, 2048, 1024);
  rope_kernel<<<dim3(16384), blk, 0, stream>>>(q_bf);
  gemm_nt64<0, 1><<<dim3(2, 256), blk, 0, stream>>>(tk_bf, wk_bf, nullptr, k_bf, 16384, 256, 256);
  gemm_nt64<0, 1><<<dim3(2, 256), blk, 0, stream>>>(tv_bf, wv_bf, nullptr, v_bf, 16384, 256, 256);
  attn_kernel<<<dim3(4, 8, 8), dim3(256), 131072, stream>>>(q_bf, k_bf, v_bf, ctx_bf);
  gemm_nt64<1, 0><<<dim3(8, 64), blk, 0, stream>>>(ctx_bf, wo_bf, x, x2, 4096, 1024, 2048);
  rmsnorm_kernel<<<dim3(4096), blk, 0, stream>>>(x2, ln2, h_bf);
  gemm256<0><<<dim3(16, 16), dim3(512), 131072, stream>>>(h_bf, wg_bf, nullptr, g_bf, 4096, 4096, 1024);
  gemm256<1><<<dim3(16, 16), dim3(512), 131072, stream>>>(h_bf, wu_bf, g_bf, g_bf, 4096, 4096, 1024);
  gemm_nt64<1, 0><<<dim3(8, 64), blk, 0, stream>>>(g_bf, wd_bf, x2, out, 4096, 1024, 4096);
}

// Round 15
// 377.325 us; speedup vs baseline: 1.9323x; 1.0648x over previous
//
#include <hip/hip_runtime.h>

typedef __attribute__((ext_vector_type(4))) float f32x4;
typedef __attribute__((ext_vector_type(8))) short s16x8;
typedef __attribute__((ext_vector_type(4))) unsigned short u16x4;

#define B_    8
#define L_    512
#define LC_   2048
#define EMBD  1024

__device__ __forceinline__ float b2f(unsigned short u) {
  unsigned int i = ((unsigned int)u) << 16;
  float f; __builtin_memcpy(&f, &i, 4); return f;
}
__device__ __forceinline__ unsigned short f2b(float f) {
  unsigned int i; __builtin_memcpy(&i, &f, 4);
  unsigned int r = i + 0x7FFFu + ((i >> 16) & 1u);
  return (unsigned short)(r >> 16);
}

#define GLL16(g, l)                                                         \
  __builtin_amdgcn_global_load_lds(                                         \
      (__attribute__((address_space(1))) void*)(g),                         \
      (__attribute__((address_space(3))) void*)(l), 16, 0, 0)

#define VMCNT6() asm volatile("s_waitcnt vmcnt(6)" ::: "memory")
#define VMCNT0() asm volatile("s_waitcnt vmcnt(0)" ::: "memory")
#define LGKM0()  asm volatile("s_waitcnt lgkmcnt(0)" ::: "memory")

// ---------------------------------------------------------------- converts (all 9 in one launch)
__global__ __launch_bounds__(256) void convert9(
    const float* s0, const float* s1, const float* s2, const float* s3,
    const float* s4, const float* s5, const float* s6, const float* s7,
    const float* s8,
    unsigned short* d0, unsigned short* d1, unsigned short* d2,
    unsigned short* d3, unsigned short* d4, unsigned short* d5,
    unsigned short* d6, unsigned short* d7, unsigned short* d8) {
  int bk = blockIdx.x;
  const float* s; unsigned short* d; int base;
  if      (bk <  2048) { s = s0; d = d0; base = 0; }
  else if (bk <  2112) { s = s1; d = d1; base = 2048; }
  else if (bk <  2176) { s = s2; d = d2; base = 2112; }
  else if (bk <  4224) { s = s3; d = d3; base = 2176; }
  else if (bk <  8320) { s = s4; d = d4; base = 4224; }
  else if (bk < 12416) { s = s5; d = d5; base = 8320; }
  else if (bk < 16512) { s = s6; d = d6; base = 12416; }
  else if (bk < 20608) { s = s7; d = d7; base = 16512; }
  else                 { s = s8; d = d8; base = 20608; }
  int i = (bk - base) * 256 + threadIdx.x;
  float4 v = ((const float4*)s)[i];
  u16x4 o = { f2b(v.x), f2b(v.y), f2b(v.z), f2b(v.w) };
  ((u16x4*)d)[i] = o;
}

// ---------------------------------------------------------------- rmsnorm
__global__ __launch_bounds__(256) void rmsnorm_kernel(
    const float* __restrict__ x, const float* __restrict__ w,
    unsigned short* __restrict__ out) {
  int row = blockIdx.x;
  int tid = threadIdx.x;
  float4 v = ((const float4*)(x + (size_t)row * EMBD))[tid];
  float ss = v.x*v.x + v.y*v.y + v.z*v.z + v.w*v.w;
#pragma unroll
  for (int o = 1; o < 64; o <<= 1) ss += __shfl_xor(ss, o);
  __shared__ float red[4];
  if ((tid & 63) == 0) red[tid >> 6] = ss;
  __syncthreads();
  float tot = red[0] + red[1] + red[2] + red[3];
  float rs = rsqrtf(tot * (1.0f / EMBD) + 1.1920928955078125e-07f);
  float4 wv = ((const float4*)w)[tid];
  u16x4 o = { f2b(v.x*rs*wv.x), f2b(v.y*rs*wv.y), f2b(v.z*rs*wv.z), f2b(v.w*rs*wv.w) };
  ((u16x4*)(out + (size_t)row * EMBD))[tid] = o;
}

// ---------------------------------------------------------------- rope (in-place on [4096][2048] bf16)
__global__ __launch_bounds__(256) void rope_kernel(unsigned short* __restrict__ q) {
  int idx = blockIdx.x * 256 + threadIdx.x;
  int i   = idx & 127;
  int h   = (idx >> 7) & 7;
  int row = idx >> 10;
  int l   = row & (L_ - 1);
  size_t base = (size_t)row * 2048 + h * 256 + i;
  float x1 = b2f(q[base]);
  float x2 = b2f(q[base + 128]);
  float ts  = powf(10000.0f, (float)i * (2.0f / 256.0f));
  float rad = (float)l / ts;
  float s, c;
  sincosf(rad, &s, &c);
  q[base]       = f2b(x1 * c - x2 * s);
  q[base + 128] = f2b(x2 * c + x1 * s);
}

// ---------------------------------------------------------------- NT GEMM 128x128 (2-barrier)
template <int ADD_RES, int OUT_BF16>
__global__ __launch_bounds__(256, 2) void gemm_nt(
    const unsigned short* __restrict__ A, const unsigned short* __restrict__ Bw,
    const float* __restrict__ Res, void* __restrict__ C, int M, int N, int K) {
  __shared__ unsigned short As[128 * 64];
  __shared__ unsigned short Bs[128 * 64];
  const int tid = threadIdx.x;
  const int lane = tid & 63, wid = tid >> 6;
  const int l15 = lane & 15, l4 = lane >> 4;
  const int wr = wid >> 1, wc = wid & 1;
  const int m0 = blockIdx.y * 128, n0 = blockIdx.x * 128;

  const f32x4 fz = {0.f, 0.f, 0.f, 0.f};
  f32x4 acc[4][4];
#pragma unroll
  for (int i = 0; i < 4; ++i)
#pragma unroll
    for (int j = 0; j < 4; ++j) acc[i][j] = fz;

  for (int k0 = 0; k0 < K; k0 += 64) {
    __syncthreads();
#pragma unroll
    for (int i = 0; i < 4; ++i) {
      int Li = i * 4096 + tid * 16;
      int row = Li >> 7;
      int kb = (Li & 127) ^ ((row & 7) << 4);
      GLL16((const char*)(A + (size_t)(m0 + row) * K + k0) + kb, (char*)As + Li);
      GLL16((const char*)(Bw + (size_t)(n0 + row) * K + k0) + kb, (char*)Bs + Li);
    }
    __syncthreads();
#pragma unroll
    for (int kk = 0; kk < 2; ++kk) {
      s16x8 af[4], bfr[4];
#pragma unroll
      for (int mi = 0; mi < 4; ++mi) {
        int row = wr * 64 + mi * 16 + l15;
        int kb = (kk * 64 + l4 * 16) ^ ((row & 7) << 4);
        af[mi] = *(const s16x8*)((const char*)As + row * 128 + kb);
      }
#pragma unroll
      for (int ni = 0; ni < 4; ++ni) {
        int row = wc * 64 + ni * 16 + l15;
        int kb = (kk * 64 + l4 * 16) ^ ((row & 7) << 4);
        bfr[ni] = *(const s16x8*)((const char*)Bs + row * 128 + kb);
      }
#pragma unroll
      for (int mi = 0; mi < 4; ++mi)
#pragma unroll
        for (int ni = 0; ni < 4; ++ni)
          acc[mi][ni] = __builtin_amdgcn_mfma_f32_16x16x32_bf16(
              af[mi], bfr[ni], acc[mi][ni], 0, 0, 0);
    }
  }
#pragma unroll
  for (int mi = 0; mi < 4; ++mi) {
#pragma unroll
    for (int r = 0; r < 4; ++r) {
      int grow = m0 + wr * 64 + mi * 16 + l4 * 4 + r;
      size_t base = (size_t)grow * N + n0 + wc * 64 + l15;
#pragma unroll
      for (int ni = 0; ni < 4; ++ni) {
        float v = acc[mi][ni][r];
        size_t idx = base + ni * 16;
        if (ADD_RES) v += Res[idx];
        if (OUT_BF16) ((unsigned short*)C)[idx] = f2b(v);
        else          ((float*)C)[idx] = v;
      }
    }
  }
}

// ---------------------------------------------------------------- NT GEMM 64x128 (512-block grids, 2/CU)
template <int ADD_RES, int OUT_BF16>
__global__ __launch_bounds__(256, 2) void gemm_nt64(
    const unsigned short* __restrict__ A, const unsigned short* __restrict__ Bw,
    const float* __restrict__ Res, void* __restrict__ C, int M, int N, int K) {
  __shared__ unsigned short As[64 * 64];
  __shared__ unsigned short Bs[128 * 64];
  const int tid = threadIdx.x;
  const int lane = tid & 63, wid = tid >> 6;
  const int l15 = lane & 15, l4 = lane >> 4;
  const int wr = wid >> 1, wc = wid & 1;
  const int m0 = blockIdx.y * 64, n0 = blockIdx.x * 128;

  const f32x4 fz = {0.f, 0.f, 0.f, 0.f};
  f32x4 acc[2][4];
#pragma unroll
  for (int i = 0; i < 2; ++i)
#pragma unroll
    for (int j = 0; j < 4; ++j) acc[i][j] = fz;

  for (int k0 = 0; k0 < K; k0 += 64) {
    __syncthreads();
#pragma unroll
    for (int i = 0; i < 2; ++i) {
      int Li = i * 4096 + tid * 16;
      int row = Li >> 7;
      int kb = (Li & 127) ^ ((row & 7) << 4);
      GLL16((const char*)(A + (size_t)(m0 + row) * K + k0) + kb, (char*)As + Li);
    }
#pragma unroll
    for (int i = 0; i < 4; ++i) {
      int Li = i * 4096 + tid * 16;
      int row = Li >> 7;
      int kb = (Li & 127) ^ ((row & 7) << 4);
      GLL16((const char*)(Bw + (size_t)(n0 + row) * K + k0) + kb, (char*)Bs + Li);
    }
    __syncthreads();
#pragma unroll
    for (int kk = 0; kk < 2; ++kk) {
      s16x8 af[2], bfr[4];
#pragma unroll
      for (int mi = 0; mi < 2; ++mi) {
        int row = wr * 32 + mi * 16 + l15;
        int kb = (kk * 64 + l4 * 16) ^ ((row & 7) << 4);
        af[mi] = *(const s16x8*)((const char*)As + row * 128 + kb);
      }
#pragma unroll
      for (int ni = 0; ni < 4; ++ni) {
        int row = wc * 64 + ni * 16 + l15;
        int kb = (kk * 64 + l4 * 16) ^ ((row & 7) << 4);
        bfr[ni] = *(const s16x8*)((const char*)Bs + row * 128 + kb);
      }
#pragma unroll
      for (int mi = 0; mi < 2; ++mi)
#pragma unroll
        for (int ni = 0; ni < 4; ++ni)
          acc[mi][ni] = __builtin_amdgcn_mfma_f32_16x16x32_bf16(
              af[mi], bfr[ni], acc[mi][ni], 0, 0, 0);
    }
  }
#pragma unroll
  for (int mi = 0; mi < 2; ++mi) {
#pragma unroll
    for (int r = 0; r < 4; ++r) {
      int grow = m0 + wr * 32 + mi * 16 + l4 * 4 + r;
      size_t base = (size_t)grow * N + n0 + wc * 64 + l15;
#pragma unroll
      for (int ni = 0; ni < 4; ++ni) {
        float v = acc[mi][ni][r];
        size_t idx = base + ni * 16;
        if (ADD_RES) v += Res[idx];
        if (OUT_BF16) ((unsigned short*)C)[idx] = f2b(v);
        else          ((float*)C)[idx] = v;
      }
    }
  }
}

// ---------------------------------------------------------------- 256x256 8-phase GEMM (T1..T5; optional fused silu(g)*acc)
template <int SWIGLU>
__global__ __launch_bounds__(512, 2) void gemm256(
    const unsigned short* __restrict__ A, const unsigned short* __restrict__ Bw,
    const unsigned short* __restrict__ G, unsigned short* __restrict__ C,
    int M, int N, int K) {
  extern __shared__ char smem[];
  const int tid = threadIdx.x;
  const int lane = tid & 63;
  const int wid = tid >> 6;
  const int wr = wid >> 2, wc = wid & 3;
  const int l15 = lane & 15, g = lane >> 4;
  int flat = blockIdx.y * 16 + blockIdx.x;
  flat = (flat & 7) * 32 + (flat >> 3);
  const int m0 = (flat >> 4) * 256, n0 = (flat & 15) * 256;
  const int T = K >> 6;
  const int swz = (l15 & 7) << 4;

  auto stage = [&](int t, int mat, int half) {
    char* dst = smem + mat * 65536 + (t & 1) * 32768 + half * 16384;
    const unsigned short* src = (mat ? Bw + (size_t)(n0 + half * 128) * K
                                     : A + (size_t)(m0 + half * 128) * K) + t * 64;
#pragma unroll
    for (int i = 0; i < 2; ++i) {
      int Li = i * 8192 + tid * 16;
      int row = Li >> 7;
      int kb = (Li & 127) ^ ((row & 7) << 4);
      GLL16((const char*)(src + (size_t)row * K) + kb, dst + Li);
    }
  };

  const f32x4 fz = {0.f, 0.f, 0.f, 0.f};
  f32x4 acc[2][2][4][2];
#pragma unroll
  for (int ms = 0; ms < 2; ++ms)
#pragma unroll
    for (int ns = 0; ns < 2; ++ns)
#pragma unroll
      for (int mi = 0; mi < 4; ++mi)
#pragma unroll
        for (int ni = 0; ni < 2; ++ni) acc[ms][ns][mi][ni] = fz;

  stage(0, 1, 0); stage(0, 1, 1); stage(0, 0, 0); stage(0, 0, 1);
  stage(1, 1, 0); stage(1, 1, 1); stage(1, 0, 0);
  VMCNT6();
  __builtin_amdgcn_s_barrier();

  for (int t = 0; t < T; ++t) {
    char* Ab = smem + (t & 1) * 32768 + wr * 16384;
    char* Bb = smem + 65536 + (t & 1) * 32768 + (wc >> 1) * 16384;
    const int bn = (wc & 1) * 64;
    s16x8 a[4][2], b0[2][2], b1[2][2];

#pragma unroll
    for (int mi = 0; mi < 4; ++mi) {
      int row = mi * 16 + l15;
#pragma unroll
      for (int kk = 0; kk < 2; ++kk)
        a[mi][kk] = *(const s16x8*)(Ab + row * 128 + ((kk * 64 + g * 16) ^ swz));
    }
#pragma unroll
    for (int ni = 0; ni < 2; ++ni) {
      int r0 = (bn + ni * 16 + l15) * 128;
      int r1 = (bn + 32 + ni * 16 + l15) * 128;
#pragma unroll
      for (int kk = 0; kk < 2; ++kk) {
        int ko = (kk * 64 + g * 16) ^ swz;
        b0[ni][kk] = *(const s16x8*)(Bb + r0 + ko);
        b1[ni][kk] = *(const s16x8*)(Bb + r1 + ko);
      }
    }
    if (t + 1 < T) stage(t + 1, 0, 1);
    __builtin_amdgcn_s_barrier();
    LGKM0();
    __builtin_amdgcn_sched_barrier(0);
    __builtin_amdgcn_s_setprio(1);
#pragma unroll
    for (int mi = 0; mi < 4; ++mi)
#pragma unroll
      for (int ni = 0; ni < 2; ++ni)
#pragma unroll
        for (int kk = 0; kk < 2; ++kk)
          acc[0][0][mi][ni] = __builtin_amdgcn_mfma_f32_16x16x32_bf16(
              a[mi][kk], b0[ni][kk], acc[0][0][mi][ni], 0, 0, 0);
    __builtin_amdgcn_s_setprio(0);
    __builtin_amdgcn_s_barrier();

    if (t + 2 < T) stage(t + 2, 1, 0);
    __builtin_amdgcn_s_barrier();
    __builtin_amdgcn_s_setprio(1);
#pragma unroll
    for (int mi = 0; mi < 4; ++mi)
#pragma unroll
      for (int ni = 0; ni < 2; ++ni)
#pragma unroll
        for (int kk = 0; kk < 2; ++kk)
          acc[0][1][mi][ni] = __builtin_amdgcn_mfma_f32_16x16x32_bf16(
              a[mi][kk], b1[ni][kk], acc[0][1][mi][ni], 0, 0, 0);
    __builtin_amdgcn_s_setprio(0);
    __builtin_amdgcn_s_barrier();

#pragma unroll
    for (int mi = 0; mi < 4; ++mi) {
      int row = 64 + mi * 16 + l15;
#pragma unroll
      for (int kk = 0; kk < 2; ++kk)
        a[mi][kk] = *(const s16x8*)(Ab + row * 128 + ((kk * 64 + g * 16) ^ swz));
    }
    if (t + 2 < T) stage(t + 2, 1, 1);
    __builtin_amdgcn_s_barrier();
    LGKM0();
    __builtin_amdgcn_sched_barrier(0);
    __builtin_amdgcn_s_setprio(1);
#pragma unroll
    for (int mi = 0; mi < 4; ++mi)
#pragma unroll
      for (int ni = 0; ni < 2; ++ni)
#pragma unroll
        for (int kk = 0; kk < 2; ++kk)
          acc[1][0][mi][ni] = __builtin_amdgcn_mfma_f32_16x16x32_bf16(
              a[mi][kk], b0[ni][kk], acc[1][0][mi][ni], 0, 0, 0);
    __builtin_amdgcn_s_setprio(0);
    __builtin_amdgcn_s_barrier();

    if (t + 2 < T) { stage(t + 2, 0, 0); VMCNT6(); }
    else           { VMCNT0(); }
    __builtin_amdgcn_s_barrier();
    __builtin_amdgcn_s_setprio(1);
#pragma unroll
    for (int mi = 0; mi < 4; ++mi)
#pragma unroll
      for (int ni = 0; ni < 2; ++ni)
#pragma unroll
        for (int kk = 0; kk < 2; ++kk)
          acc[1][1][mi][ni] = __builtin_amdgcn_mfma_f32_16x16x32_bf16(
              a[mi][kk], b1[ni][kk], acc[1][1][mi][ni], 0, 0, 0);
    __builtin_amdgcn_s_setprio(0);
    __builtin_amdgcn_s_barrier();
  }

#pragma unroll
  for (int ms = 0; ms < 2; ++ms)
#pragma unroll
    for (int mi = 0; mi < 4; ++mi)
#pragma unroll
      for (int r = 0; r < 4; ++r) {
        int grow = m0 + wr * 128 + ms * 64 + mi * 16 + g * 4 + r;
        size_t base = (size_t)grow * N + n0 + wc * 64;
#pragma unroll
        for (int ns = 0; ns < 2; ++ns)
#pragma unroll
          for (int ni = 0; ni < 2; ++ni) {
            size_t idx = base + ns * 32 + ni * 16 + l15;
            float v = acc[ms][ns][mi][ni][r];
            if (SWIGLU) {
              float gf = b2f(G[idx]);
              v *= gf / (1.0f + __expf(-gf));
            }
            C[idx] = f2b(v);
          }
      }
}

// ---------------------------------------------------------------- fused attention (O^T PV, zero-shuffle; full KV per block)
// grid (qt=4, h=8, b=8) = 256 blocks, 512 thr (8 waves x 16 q-rows), 32 KV
// tiles/block (R11 body, split-KV and merge removed; Ctx written directly).
// K staged with PERMUTED source rows (kv = (mi>>1)*32 + g*8 + (mi&1)*4 + r)
// so lane's packed P words are exactly the PV B-fragment; O^T = mfma(V^T, P^T)
// keeps q = l15 lane-local: no cross-lane ops in PV/rescale/normalize.
#define SWZV(d) (((((d) & 7) ^ (((d) >> 3) & 7))) << 4)

__global__ __launch_bounds__(512, 2) void attn_kernel(
    const unsigned short* __restrict__ Q,   // [4096][2048] (roped)
    const unsigned short* __restrict__ Kc,  // [B][2048][256]
    const unsigned short* __restrict__ Vc,  // [B][2048][256]
    unsigned short* __restrict__ Ctx) {     // [4096][2048]
  __shared__ unsigned short Ks[64 * 256];   // 32KB, row 512B, swizzled, kv-permuted
  __shared__ unsigned short Vt[256 * 64];   // 32KB, [d][kv], swizzled
  const int tid = threadIdx.x;
  const int lane = tid & 63, wid = tid >> 6;
  const int l15 = lane & 15, g = lane >> 4;
  const int qt = blockIdx.x, h = blockIdx.y, b = blockIdx.z;

  const size_t qrow = (size_t)(b * L_ + qt * 128 + wid * 16 + l15);
  const unsigned short* qp = Q + qrow * 2048 + h * 256;
  s16x8 qf[8];
#pragma unroll
  for (int kc = 0; kc < 8; ++kc) qf[kc] = *(const s16x8*)(qp + kc * 32 + g * 8);

  const f32x4 fz = {0.f, 0.f, 0.f, 0.f};
  f32x4 oacc[16];   // O^T: oacc[nd][r] = O[q=l15][d = nd*16 + g*4 + r]
#pragma unroll
  for (int i = 0; i < 16; ++i) oacc[i] = fz;
  float m_run = -__builtin_inff(), l_run = 0.f;

  const unsigned short* Kb = Kc + (size_t)b * LC_ * 256;
  const unsigned short* Vb = Vc + (size_t)b * LC_ * 256;

  for (int kt = 0; kt < LC_ / 64; ++kt) {
    __syncthreads();
    // stage K: dest row rr holds K[kvperm(rr)]; source row permuted, byte
    // swizzle unchanged (dest-row based)
#pragma unroll
    for (int i = 0; i < 4; ++i) {
      int Li = i * 8192 + tid * 16;
      int row = Li >> 9;
      int mi = row >> 4;
      int kvp = ((mi >> 1) << 5) | (((row >> 2) & 3) << 3) | ((mi & 1) << 2) | (row & 3);
      int kb = (Li & 511) ^ ((row & 7) << 4);
      GLL16((const char*)(Kb + (size_t)(kt * 64 + kvp) * 256) + kb, (char*)Ks + Li);
    }
    // stage V transposed (Vt[d][kv], b32 pair writes; true kv order)
#pragma unroll
    for (int p = 0; p < 2; ++p) {
      int id = p * 512 + tid;
      int dgrp = id & 31, kvp2 = id >> 5;
      int d0 = dgrp * 8, kv0 = kvp2 * 2;
      const unsigned short* v0p = Vb + (size_t)(kt * 64 + kv0) * 256 + d0;
      s16x8 r0 = *(const s16x8*)v0p;
      s16x8 r1 = *(const s16x8*)(v0p + 256);
#pragma unroll
      for (int j = 0; j < 8; ++j) {
        int d = d0 + j;
        unsigned int val = (unsigned int)(unsigned short)r0[j] |
                           ((unsigned int)(unsigned short)r1[j] << 16);
        *(unsigned int*)((char*)Vt + d * 128 + ((kv0 * 2) ^ SWZV(d))) = val;
      }
    }
    __syncthreads();

    // S^T = K * Q^T (rows = permuted kv, cols = q)
    f32x4 sacc[4];
#pragma unroll
    for (int mi = 0; mi < 4; ++mi) sacc[mi] = fz;
#pragma unroll
    for (int mi = 0; mi < 4; ++mi) {
      int row = mi * 16 + l15;
      int swz = (row & 7) << 4;
#pragma unroll
      for (int kc = 0; kc < 8; ++kc) {
        s16x8 kf = *(const s16x8*)((const char*)Ks + row * 512 + ((kc * 64 + g * 16) ^ swz));
        sacc[mi] = __builtin_amdgcn_mfma_f32_16x16x32_bf16(kf, qf[kc], sacc[mi], 0, 0, 0);
      }
    }
    // online softmax with defer-max (THR=8); all reductions kv-order-agnostic
    float sv[4][4];
    float mt = -__builtin_inff();
#pragma unroll
    for (int mi = 0; mi < 4; ++mi)
#pragma unroll
      for (int r = 0; r < 4; ++r) {
        float t = sacc[mi][r] * 0.0625f;
        sv[mi][r] = t;
        mt = fmaxf(mt, t);
      }
    mt = fmaxf(mt, __shfl_xor(mt, 16));
    mt = fmaxf(mt, __shfl_xor(mt, 32));
    if (!__all(mt <= m_run + 8.0f)) {
      float mnew = fmaxf(m_run, mt);
      float alpha = __expf(m_run - mnew);   // lane-local: q = l15 owns O^T cols
#pragma unroll
      for (int nd = 0; nd < 16; ++nd)
#pragma unroll
        for (int r = 0; r < 4; ++r) oacc[nd][r] *= alpha;
      l_run *= alpha;
      m_run = mnew;
    }
    float rs = 0.f;
#pragma unroll
    for (int mi = 0; mi < 4; ++mi)
#pragma unroll
      for (int r = 0; r < 4; ++r) {
        float p = __expf(sv[mi][r] - m_run);
        sv[mi][r] = p;
        rs += p;
      }
    rs += __shfl_xor(rs, 16);
    rs += __shfl_xor(rs, 32);
    l_run += rs;
    // pack P: pk[mi][rp] = kv {perm(mi,g,2rp), +1}; lane-local B-frag (P^T)
    unsigned int pk[4][2];
#pragma unroll
    for (int ni = 0; ni < 4; ++ni) {
      pk[ni][0] = (unsigned int)f2b(sv[ni][0]) | ((unsigned int)f2b(sv[ni][1]) << 16);
      pk[ni][1] = (unsigned int)f2b(sv[ni][2]) | ((unsigned int)f2b(sv[ni][3]) << 16);
    }
    // PV: O^T accum; A = V^T-frag from Vt, B = pk words
#pragma unroll
    for (int tt = 0; tt < 2; ++tt) {
      union { unsigned int u[4]; s16x8 v; } pf;
      pf.u[0] = pk[2 * tt][0];
      pf.u[1] = pk[2 * tt][1];
      pf.u[2] = pk[2 * tt + 1][0];
      pf.u[3] = pk[2 * tt + 1][1];
#pragma unroll
      for (int nd = 0; nd < 16; ++nd) {
        int d = nd * 16 + l15;
        s16x8 vf = *(const s16x8*)((const char*)Vt + d * 128 + ((tt * 64 + g * 16) ^ SWZV(d)));
        oacc[nd] = __builtin_amdgcn_mfma_f32_16x16x32_bf16(vf, pf.v, oacc[nd], 0, 0, 0);
      }
    }
  }
  // store normalized O directly to Ctx (b64 per nd); all lane-local
  float lf = 1.0f / l_run;
  const size_t base = (qrow) * 2048 + h * 256 + g * 4;
#pragma unroll
  for (int nd = 0; nd < 16; ++nd) {
    u16x4 o = { f2b(oacc[nd][0] * lf), f2b(oacc[nd][1] * lf),
                f2b(oacc[nd][2] * lf), f2b(oacc[nd][3] * lf) };
    *(u16x4*)(Ctx + base + nd * 16) = o;
  }
}

// ---------------------------------------------------------------- launch
extern "C" void kernel_launch(void* const* d_in, const int* in_sizes, int n_in,
                              void* d_out, int out_size, void* d_ws, size_t ws_size,
                              hipStream_t stream) {
  const float* x   = (const float*)d_in[0];
  const float* tk  = (const float*)d_in[1];
  const float* tv  = (const float*)d_in[2];
  const float* ln1 = (const float*)d_in[3];
  const float* ln2 = (const float*)d_in[4];
  const float* Wq  = (const float*)d_in[5];
  const float* Wk  = (const float*)d_in[6];
  const float* Wv  = (const float*)d_in[7];
  const float* Wo  = (const float*)d_in[8];
  const float* Wg  = (const float*)d_in[9];
  const float* Wu  = (const float*)d_in[10];
  const float* Wd  = (const float*)d_in[11];
  float* out = (float*)d_out;
  char* ws = (char*)d_ws;

  (void)hipFuncSetAttribute((const void*)gemm256<0>,
                            hipFuncAttributeMaxDynamicSharedMemorySize, 131072);
  (void)hipFuncSetAttribute((const void*)gemm256<1>,
                            hipFuncAttributeMaxDynamicSharedMemorySize, 131072);

  // workspace layout (126.1 MB, lifetime-based aliasing)
  unsigned short* tk_bf  = (unsigned short*)(ws + 0);
  unsigned short* tv_bf  = (unsigned short*)(ws + 8388608);
  unsigned short* k_bf   = (unsigned short*)(ws + 16777216);
  unsigned short* v_bf   = (unsigned short*)(ws + 25165824);
  unsigned short* g_bf   = (unsigned short*)(ws + 0);         // FFN gate (tk/tv dead)
  unsigned short* q_bf   = (unsigned short*)(ws + 33554432);
  unsigned short* ctx_bf = (unsigned short*)(ws + 50331648);
  unsigned short* u_bf   = (unsigned short*)(ws + 33554432);  // aliases q (dead)
  unsigned short* wq_bf  = (unsigned short*)(ws + 67108864);
  unsigned short* wk_bf  = (unsigned short*)(ws + 71303168);
  unsigned short* wv_bf  = (unsigned short*)(ws + 71434240);
  unsigned short* wo_bf  = (unsigned short*)(ws + 71565312);
  unsigned short* wg_bf  = (unsigned short*)(ws + 75759616);
  unsigned short* wu_bf  = (unsigned short*)(ws + 84148224);
  unsigned short* wd_bf  = (unsigned short*)(ws + 92536832);
  unsigned short* h_bf   = (unsigned short*)(ws + 100925440);
  float*          x2     = (float*)(ws + 109314048);

  dim3 blk(256);
  convert9<<<dim3(24704), blk, 0, stream>>>(
      Wq, Wk, Wv, Wo, Wg, Wu, Wd, tk, tv,
      wq_bf, wk_bf, wv_bf, wo_bf, wg_bf, wu_bf, wd_bf, tk_bf, tv_bf);

  rmsnorm_kernel<<<dim3(4096), blk, 0, stream>>>(x, ln1, h_bf);
  gemm_nt<0, 1><<<dim3(16, 32), blk, 0, stream>>>(h_bf, wq_bf, nullptr, q_bf, 4096, 2048, 1024);
  rope_kernel<<<dim3(16384), blk, 0, stream>>>(q_bf);
  gemm_nt64<0, 1><<<dim3(2, 256), blk, 0, stream>>>(tk_bf, wk_bf, nullptr, k_bf, 16384, 256, 256);
  gemm_nt64<0, 1><<<dim3(2, 256), blk, 0, stream>>>(tv_bf, wv_bf, nullptr, v_bf, 16384, 256, 256);
  attn_kernel<<<dim3(4, 8, 8), dim3(512), 0, stream>>>(q_bf, k_bf, v_bf, ctx_bf);
  gemm_nt64<1, 0><<<dim3(8, 64), blk, 0, stream>>>(ctx_bf, wo_bf, x, x2, 4096, 1024, 2048);
  rmsnorm_kernel<<<dim3(4096), blk, 0, stream>>>(x2, ln2, h_bf);
  gemm256<0><<<dim3(16, 16), dim3(512), 131072, stream>>>(h_bf, wg_bf, nullptr, g_bf, 4096, 4096, 1024);
  gemm256<1><<<dim3(16, 16), dim3(512), 131072, stream>>>(h_bf, wu_bf, g_bf, g_bf, 4096, 4096, 1024);
  gemm_nt64<1, 0><<<dim3(8, 64), blk, 0, stream>>>(g_bf, wd_bf, x2, out, 4096, 1024, 4096);
}

// Round 16
// 359.959 us; speedup vs baseline: 2.0256x; 1.0482x over previous
//
#include <hip/hip_runtime.h>

typedef __attribute__((ext_vector_type(4))) float f32x4;
typedef __attribute__((ext_vector_type(8))) short s16x8;
typedef __attribute__((ext_vector_type(4))) unsigned short u16x4;

#define B_    8
#define L_    512
#define LC_   2048
#define EMBD  1024

__device__ __forceinline__ float b2f(unsigned short u) {
  unsigned int i = ((unsigned int)u) << 16;
  float f; __builtin_memcpy(&f, &i, 4); return f;
}
__device__ __forceinline__ unsigned short f2b(float f) {
  unsigned int i; __builtin_memcpy(&i, &f, 4);
  unsigned int r = i + 0x7FFFu + ((i >> 16) & 1u);
  return (unsigned short)(r >> 16);
}

#define GLL16(g, l)                                                         \
  __builtin_amdgcn_global_load_lds(                                         \
      (__attribute__((address_space(1))) void*)(g),                         \
      (__attribute__((address_space(3))) void*)(l), 16, 0, 0)

#define VMCNT6() asm volatile("s_waitcnt vmcnt(6)" ::: "memory")
#define VMCNT0() asm volatile("s_waitcnt vmcnt(0)" ::: "memory")
#define LGKM0()  asm volatile("s_waitcnt lgkmcnt(0)" ::: "memory")

// ---------------------------------------------------------------- converts (all 9 in one launch)
__global__ __launch_bounds__(256) void convert9(
    const float* s0, const float* s1, const float* s2, const float* s3,
    const float* s4, const float* s5, const float* s6, const float* s7,
    const float* s8,
    unsigned short* d0, unsigned short* d1, unsigned short* d2,
    unsigned short* d3, unsigned short* d4, unsigned short* d5,
    unsigned short* d6, unsigned short* d7, unsigned short* d8) {
  int bk = blockIdx.x;
  const float* s; unsigned short* d; int base;
  if      (bk <  2048) { s = s0; d = d0; base = 0; }
  else if (bk <  2112) { s = s1; d = d1; base = 2048; }
  else if (bk <  2176) { s = s2; d = d2; base = 2112; }
  else if (bk <  4224) { s = s3; d = d3; base = 2176; }
  else if (bk <  8320) { s = s4; d = d4; base = 4224; }
  else if (bk < 12416) { s = s5; d = d5; base = 8320; }
  else if (bk < 16512) { s = s6; d = d6; base = 12416; }
  else if (bk < 20608) { s = s7; d = d7; base = 16512; }
  else                 { s = s8; d = d8; base = 20608; }
  int i = (bk - base) * 256 + threadIdx.x;
  float4 v = ((const float4*)s)[i];
  u16x4 o = { f2b(v.x), f2b(v.y), f2b(v.z), f2b(v.w) };
  ((u16x4*)d)[i] = o;
}

// ---------------------------------------------------------------- rmsnorm
__global__ __launch_bounds__(256) void rmsnorm_kernel(
    const float* __restrict__ x, const float* __restrict__ w,
    unsigned short* __restrict__ out) {
  int row = blockIdx.x;
  int tid = threadIdx.x;
  float4 v = ((const float4*)(x + (size_t)row * EMBD))[tid];
  float ss = v.x*v.x + v.y*v.y + v.z*v.z + v.w*v.w;
#pragma unroll
  for (int o = 1; o < 64; o <<= 1) ss += __shfl_xor(ss, o);
  __shared__ float red[4];
  if ((tid & 63) == 0) red[tid >> 6] = ss;
  __syncthreads();
  float tot = red[0] + red[1] + red[2] + red[3];
  float rs = rsqrtf(tot * (1.0f / EMBD) + 1.1920928955078125e-07f);
  float4 wv = ((const float4*)w)[tid];
  u16x4 o = { f2b(v.x*rs*wv.x), f2b(v.y*rs*wv.y), f2b(v.z*rs*wv.z), f2b(v.w*rs*wv.w) };
  ((u16x4*)(out + (size_t)row * EMBD))[tid] = o;
}

// ---------------------------------------------------------------- rope table (unique (l,i) trig values)
__global__ __launch_bounds__(256) void rope_table(float2* __restrict__ tab) {
  int idx = blockIdx.x * 256 + threadIdx.x;   // 512*128
  int i = idx & 127, l = idx >> 7;
  float ts  = powf(10000.0f, (float)i * (2.0f / 256.0f));
  float rad = (float)l / ts;
  float s, c;
  sincosf(rad, &s, &c);
  tab[idx] = make_float2(c, s);
}

// ---------------------------------------------------------------- rope (in-place, table-driven: pure BW)
__global__ __launch_bounds__(256) void rope_kernel(
    unsigned short* __restrict__ q, const float2* __restrict__ tab) {
  int idx = blockIdx.x * 256 + threadIdx.x;   // 4096*8*128
  int i   = idx & 127;
  int h   = (idx >> 7) & 7;
  int row = idx >> 10;
  int l   = row & (L_ - 1);
  size_t base = (size_t)row * 2048 + h * 256 + i;
  float x1 = b2f(q[base]);
  float x2 = b2f(q[base + 128]);
  float2 cs = tab[(l << 7) + i];
  q[base]       = f2b(x1 * cs.x - x2 * cs.y);
  q[base + 128] = f2b(x2 * cs.x + x1 * cs.y);
}

// ---------------------------------------------------------------- V transpose+swizzle to global (once)
// VtG[b][kt][d][kv'] tile-major (32KB/tile), byte layout IDENTICAL to the old
// in-attn writeV: byte (d*128 + ((kv*2)^SWZV(d))) holds V[kt*64+kv][d].
#define SWZV(d) (((((d) & 7) ^ (((d) >> 3) & 7))) << 4)
__global__ __launch_bounds__(256) void vtrans_kernel(
    const unsigned short* __restrict__ V,   // [B][2048][256]
    unsigned short* __restrict__ VtG) {     // [B][32][32KB]
  const int kt = blockIdx.x, b = blockIdx.y;
  const int tid = threadIdx.x;
  const int dgrp = tid & 31, kvq = tid >> 5;     // d0 = dgrp*8, kv0 = kvq*8
  const int d0 = dgrp * 8, kv0 = kvq * 8;
  const unsigned short* vp = V + ((size_t)b * LC_ + kt * 64 + kv0) * 256 + d0;
  s16x8 r[8];
#pragma unroll
  for (int jj = 0; jj < 8; ++jj) r[jj] = *(const s16x8*)(vp + jj * 256);
  char* tb = (char*)VtG + (((size_t)b * 32 + kt) << 15);
#pragma unroll
  for (int j = 0; j < 8; ++j) {
    int d = d0 + j;
    union { unsigned int u[4]; s16x8 v; } w;
#pragma unroll
    for (int p = 0; p < 4; ++p)
      w.u[p] = (unsigned int)(unsigned short)r[2 * p][j] |
               ((unsigned int)(unsigned short)r[2 * p + 1][j] << 16);
    *(s16x8*)(tb + d * 128 + ((kv0 * 2) ^ SWZV(d))) = w.v;
  }
}

// ---------------------------------------------------------------- NT GEMM 128x128 (2-barrier)
template <int ADD_RES, int OUT_BF16>
__global__ __launch_bounds__(256, 2) void gemm_nt(
    const unsigned short* __restrict__ A, const unsigned short* __restrict__ Bw,
    const float* __restrict__ Res, void* __restrict__ C, int M, int N, int K) {
  __shared__ unsigned short As[128 * 64];
  __shared__ unsigned short Bs[128 * 64];
  const int tid = threadIdx.x;
  const int lane = tid & 63, wid = tid >> 6;
  const int l15 = lane & 15, l4 = lane >> 4;
  const int wr = wid >> 1, wc = wid & 1;
  const int m0 = blockIdx.y * 128, n0 = blockIdx.x * 128;

  const f32x4 fz = {0.f, 0.f, 0.f, 0.f};
  f32x4 acc[4][4];
#pragma unroll
  for (int i = 0; i < 4; ++i)
#pragma unroll
    for (int j = 0; j < 4; ++j) acc[i][j] = fz;

  for (int k0 = 0; k0 < K; k0 += 64) {
    __syncthreads();
#pragma unroll
    for (int i = 0; i < 4; ++i) {
      int Li = i * 4096 + tid * 16;
      int row = Li >> 7;
      int kb = (Li & 127) ^ ((row & 7) << 4);
      GLL16((const char*)(A + (size_t)(m0 + row) * K + k0) + kb, (char*)As + Li);
      GLL16((const char*)(Bw + (size_t)(n0 + row) * K + k0) + kb, (char*)Bs + Li);
    }
    __syncthreads();
#pragma unroll
    for (int kk = 0; kk < 2; ++kk) {
      s16x8 af[4], bfr[4];
#pragma unroll
      for (int mi = 0; mi < 4; ++mi) {
        int row = wr * 64 + mi * 16 + l15;
        int kb = (kk * 64 + l4 * 16) ^ ((row & 7) << 4);
        af[mi] = *(const s16x8*)((const char*)As + row * 128 + kb);
      }
#pragma unroll
      for (int ni = 0; ni < 4; ++ni) {
        int row = wc * 64 + ni * 16 + l15;
        int kb = (kk * 64 + l4 * 16) ^ ((row & 7) << 4);
        bfr[ni] = *(const s16x8*)((const char*)Bs + row * 128 + kb);
      }
#pragma unroll
      for (int mi = 0; mi < 4; ++mi)
#pragma unroll
        for (int ni = 0; ni < 4; ++ni)
          acc[mi][ni] = __builtin_amdgcn_mfma_f32_16x16x32_bf16(
              af[mi], bfr[ni], acc[mi][ni], 0, 0, 0);
    }
  }
#pragma unroll
  for (int mi = 0; mi < 4; ++mi) {
#pragma unroll
    for (int r = 0; r < 4; ++r) {
      int grow = m0 + wr * 64 + mi * 16 + l4 * 4 + r;
      size_t base = (size_t)grow * N + n0 + wc * 64 + l15;
#pragma unroll
      for (int ni = 0; ni < 4; ++ni) {
        float v = acc[mi][ni][r];
        size_t idx = base + ni * 16;
        if (ADD_RES) v += Res[idx];
        if (OUT_BF16) ((unsigned short*)C)[idx] = f2b(v);
        else          ((float*)C)[idx] = v;
      }
    }
  }
}

// ---------------------------------------------------------------- NT GEMM 64x128 (512-block grids, 2/CU)
template <int ADD_RES, int OUT_BF16>
__global__ __launch_bounds__(256, 2) void gemm_nt64(
    const unsigned short* __restrict__ A, const unsigned short* __restrict__ Bw,
    const float* __restrict__ Res, void* __restrict__ C, int M, int N, int K) {
  __shared__ unsigned short As[64 * 64];
  __shared__ unsigned short Bs[128 * 64];
  const int tid = threadIdx.x;
  const int lane = tid & 63, wid = tid >> 6;
  const int l15 = lane & 15, l4 = lane >> 4;
  const int wr = wid >> 1, wc = wid & 1;
  const int m0 = blockIdx.y * 64, n0 = blockIdx.x * 128;

  const f32x4 fz = {0.f, 0.f, 0.f, 0.f};
  f32x4 acc[2][4];
#pragma unroll
  for (int i = 0; i < 2; ++i)
#pragma unroll
    for (int j = 0; j < 4; ++j) acc[i][j] = fz;

  for (int k0 = 0; k0 < K; k0 += 64) {
    __syncthreads();
#pragma unroll
    for (int i = 0; i < 2; ++i) {
      int Li = i * 4096 + tid * 16;
      int row = Li >> 7;
      int kb = (Li & 127) ^ ((row & 7) << 4);
      GLL16((const char*)(A + (size_t)(m0 + row) * K + k0) + kb, (char*)As + Li);
    }
#pragma unroll
    for (int i = 0; i < 4; ++i) {
      int Li = i * 4096 + tid * 16;
      int row = Li >> 7;
      int kb = (Li & 127) ^ ((row & 7) << 4);
      GLL16((const char*)(Bw + (size_t)(n0 + row) * K + k0) + kb, (char*)Bs + Li);
    }
    __syncthreads();
#pragma unroll
    for (int kk = 0; kk < 2; ++kk) {
      s16x8 af[2], bfr[4];
#pragma unroll
      for (int mi = 0; mi < 2; ++mi) {
        int row = wr * 32 + mi * 16 + l15;
        int kb = (kk * 64 + l4 * 16) ^ ((row & 7) << 4);
        af[mi] = *(const s16x8*)((const char*)As + row * 128 + kb);
      }
#pragma unroll
      for (int ni = 0; ni < 4; ++ni) {
        int row = wc * 64 + ni * 16 + l15;
        int kb = (kk * 64 + l4 * 16) ^ ((row & 7) << 4);
        bfr[ni] = *(const s16x8*)((const char*)Bs + row * 128 + kb);
      }
#pragma unroll
      for (int mi = 0; mi < 2; ++mi)
#pragma unroll
        for (int ni = 0; ni < 4; ++ni)
          acc[mi][ni] = __builtin_amdgcn_mfma_f32_16x16x32_bf16(
              af[mi], bfr[ni], acc[mi][ni], 0, 0, 0);
    }
  }
#pragma unroll
  for (int mi = 0; mi < 2; ++mi) {
#pragma unroll
    for (int r = 0; r < 4; ++r) {
      int grow = m0 + wr * 32 + mi * 16 + l4 * 4 + r;
      size_t base = (size_t)grow * N + n0 + wc * 64 + l15;
#pragma unroll
      for (int ni = 0; ni < 4; ++ni) {
        float v = acc[mi][ni][r];
        size_t idx = base + ni * 16;
        if (ADD_RES) v += Res[idx];
        if (OUT_BF16) ((unsigned short*)C)[idx] = f2b(v);
        else          ((float*)C)[idx] = v;
      }
    }
  }
}

// ---------------------------------------------------------------- 256x256 8-phase GEMM (T1..T5; optional fused silu(g)*acc)
template <int SWIGLU>
__global__ __launch_bounds__(512, 2) void gemm256(
    const unsigned short* __restrict__ A, const unsigned short* __restrict__ Bw,
    const unsigned short* __restrict__ G, unsigned short* __restrict__ C,
    int M, int N, int K) {
  extern __shared__ char smem[];
  const int tid = threadIdx.x;
  const int lane = tid & 63;
  const int wid = tid >> 6;
  const int wr = wid >> 2, wc = wid & 3;
  const int l15 = lane & 15, g = lane >> 4;
  int flat = blockIdx.y * 16 + blockIdx.x;
  flat = (flat & 7) * 32 + (flat >> 3);
  const int m0 = (flat >> 4) * 256, n0 = (flat & 15) * 256;
  const int T = K >> 6;
  const int swz = (l15 & 7) << 4;

  auto stage = [&](int t, int mat, int half) {
    char* dst = smem + mat * 65536 + (t & 1) * 32768 + half * 16384;
    const unsigned short* src = (mat ? Bw + (size_t)(n0 + half * 128) * K
                                     : A + (size_t)(m0 + half * 128) * K) + t * 64;
#pragma unroll
    for (int i = 0; i < 2; ++i) {
      int Li = i * 8192 + tid * 16;
      int row = Li >> 7;
      int kb = (Li & 127) ^ ((row & 7) << 4);
      GLL16((const char*)(src + (size_t)row * K) + kb, dst + Li);
    }
  };

  const f32x4 fz = {0.f, 0.f, 0.f, 0.f};
  f32x4 acc[2][2][4][2];
#pragma unroll
  for (int ms = 0; ms < 2; ++ms)
#pragma unroll
    for (int ns = 0; ns < 2; ++ns)
#pragma unroll
      for (int mi = 0; mi < 4; ++mi)
#pragma unroll
        for (int ni = 0; ni < 2; ++ni) acc[ms][ns][mi][ni] = fz;

  stage(0, 1, 0); stage(0, 1, 1); stage(0, 0, 0); stage(0, 0, 1);
  stage(1, 1, 0); stage(1, 1, 1); stage(1, 0, 0);
  VMCNT6();
  __builtin_amdgcn_s_barrier();

  for (int t = 0; t < T; ++t) {
    char* Ab = smem + (t & 1) * 32768 + wr * 16384;
    char* Bb = smem + 65536 + (t & 1) * 32768 + (wc >> 1) * 16384;
    const int bn = (wc & 1) * 64;
    s16x8 a[4][2], b0[2][2], b1[2][2];

#pragma unroll
    for (int mi = 0; mi < 4; ++mi) {
      int row = mi * 16 + l15;
#pragma unroll
      for (int kk = 0; kk < 2; ++kk)
        a[mi][kk] = *(const s16x8*)(Ab + row * 128 + ((kk * 64 + g * 16) ^ swz));
    }
#pragma unroll
    for (int ni = 0; ni < 2; ++ni) {
      int r0 = (bn + ni * 16 + l15) * 128;
      int r1 = (bn + 32 + ni * 16 + l15) * 128;
#pragma unroll
      for (int kk = 0; kk < 2; ++kk) {
        int ko = (kk * 64 + g * 16) ^ swz;
        b0[ni][kk] = *(const s16x8*)(Bb + r0 + ko);
        b1[ni][kk] = *(const s16x8*)(Bb + r1 + ko);
      }
    }
    if (t + 1 < T) stage(t + 1, 0, 1);
    __builtin_amdgcn_s_barrier();
    LGKM0();
    __builtin_amdgcn_sched_barrier(0);
    __builtin_amdgcn_s_setprio(1);
#pragma unroll
    for (int mi = 0; mi < 4; ++mi)
#pragma unroll
      for (int ni = 0; ni < 2; ++ni)
#pragma unroll
        for (int kk = 0; kk < 2; ++kk)
          acc[0][0][mi][ni] = __builtin_amdgcn_mfma_f32_16x16x32_bf16(
              a[mi][kk], b0[ni][kk], acc[0][0][mi][ni], 0, 0, 0);
    __builtin_amdgcn_s_setprio(0);
    __builtin_amdgcn_s_barrier();

    if (t + 2 < T) stage(t + 2, 1, 0);
    __builtin_amdgcn_s_barrier();
    __builtin_amdgcn_s_setprio(1);
#pragma unroll
    for (int mi = 0; mi < 4; ++mi)
#pragma unroll
      for (int ni = 0; ni < 2; ++ni)
#pragma unroll
        for (int kk = 0; kk < 2; ++kk)
          acc[0][1][mi][ni] = __builtin_amdgcn_mfma_f32_16x16x32_bf16(
              a[mi][kk], b1[ni][kk], acc[0][1][mi][ni], 0, 0, 0);
    __builtin_amdgcn_s_setprio(0);
    __builtin_amdgcn_s_barrier();

#pragma unroll
    for (int mi = 0; mi < 4; ++mi) {
      int row = 64 + mi * 16 + l15;
#pragma unroll
      for (int kk = 0; kk < 2; ++kk)
        a[mi][kk] = *(const s16x8*)(Ab + row * 128 + ((kk * 64 + g * 16) ^ swz));
    }
    if (t + 2 < T) stage(t + 2, 1, 1);
    __builtin_amdgcn_s_barrier();
    LGKM0();
    __builtin_amdgcn_sched_barrier(0);
    __builtin_amdgcn_s_setprio(1);
#pragma unroll
    for (int mi = 0; mi < 4; ++mi)
#pragma unroll
      for (int ni = 0; ni < 2; ++ni)
#pragma unroll
        for (int kk = 0; kk < 2; ++kk)
          acc[1][0][mi][ni] = __builtin_amdgcn_mfma_f32_16x16x32_bf16(
              a[mi][kk], b0[ni][kk], acc[1][0][mi][ni], 0, 0, 0);
    __builtin_amdgcn_s_setprio(0);
    __builtin_amdgcn_s_barrier();

    if (t + 2 < T) { stage(t + 2, 0, 0); VMCNT6(); }
    else           { VMCNT0(); }
    __builtin_amdgcn_s_barrier();
    __builtin_amdgcn_s_setprio(1);
#pragma unroll
    for (int mi = 0; mi < 4; ++mi)
#pragma unroll
      for (int ni = 0; ni < 2; ++ni)
#pragma unroll
        for (int kk = 0; kk < 2; ++kk)
          acc[1][1][mi][ni] = __builtin_amdgcn_mfma_f32_16x16x32_bf16(
              a[mi][kk], b1[ni][kk], acc[1][1][mi][ni], 0, 0, 0);
    __builtin_amdgcn_s_setprio(0);
    __builtin_amdgcn_s_barrier();
  }

#pragma unroll
  for (int ms = 0; ms < 2; ++ms)
#pragma unroll
    for (int mi = 0; mi < 4; ++mi)
#pragma unroll
      for (int r = 0; r < 4; ++r) {
        int grow = m0 + wr * 128 + ms * 64 + mi * 16 + g * 4 + r;
        size_t base = (size_t)grow * N + n0 + wc * 64;
#pragma unroll
        for (int ns = 0; ns < 2; ++ns)
#pragma unroll
          for (int ni = 0; ni < 2; ++ni) {
            size_t idx = base + ns * 32 + ni * 16 + l15;
            float v = acc[ms][ns][mi][ni][r];
            if (SWIGLU) {
              float gf = b2f(G[idx]);
              v *= gf / (1.0f + __expf(-gf));
            }
            C[idx] = f2b(v);
          }
      }
}

// ---------------------------------------------------------------- fused attention (O^T PV, zero-shuffle; pure-GLL16 staging)
// grid (qt=4, h=8, b=8) = 256 blocks, 512 thr (8 waves x 16 q-rows), 32 KV
// tiles/block. V pre-transposed+swizzled in VtG (vtrans) -> V staging is 4
// linear GLL16s (no reg round-trip, no LDS writes, no pack VALU). K staged
// with PERMUTED source rows so lane's packed P words form the PV B-fragment;
// O^T = mfma(V^T, P^T) keeps q = l15 lane-local (no cross-lane in PV).
__global__ __launch_bounds__(512, 2) void attn_kernel(
    const unsigned short* __restrict__ Q,    // [4096][2048] (roped)
    const unsigned short* __restrict__ Kc,   // [B][2048][256]
    const unsigned short* __restrict__ VtG,  // [B][32][32KB] pre-swizzled
    unsigned short* __restrict__ Ctx) {      // [4096][2048]
  __shared__ unsigned short Ks[64 * 256];   // 32KB, row 512B, swizzled, kv-permuted
  __shared__ unsigned short Vt[256 * 64];   // 32KB, [d][kv], swizzled
  const int tid = threadIdx.x;
  const int lane = tid & 63, wid = tid >> 6;
  const int l15 = lane & 15, g = lane >> 4;
  const int qt = blockIdx.x, h = blockIdx.y, b = blockIdx.z;

  const size_t qrow = (size_t)(b * L_ + qt * 128 + wid * 16 + l15);
  const unsigned short* qp = Q + qrow * 2048 + h * 256;
  s16x8 qf[8];
#pragma unroll
  for (int kc = 0; kc < 8; ++kc) qf[kc] = *(const s16x8*)(qp + kc * 32 + g * 8);

  const f32x4 fz = {0.f, 0.f, 0.f, 0.f};
  f32x4 oacc[16];   // O^T: oacc[nd][r] = O[q=l15][d = nd*16 + g*4 + r]
#pragma unroll
  for (int i = 0; i < 16; ++i) oacc[i] = fz;
  float m_run = -__builtin_inff(), l_run = 0.f;

  const unsigned short* Kb = Kc + (size_t)b * LC_ * 256;
  const char* Vb = (const char*)VtG + ((size_t)b << 20);   // b*32 tiles*32KB

  for (int kt = 0; kt < LC_ / 64; ++kt) {
    __syncthreads();
    // stage K: dest row rr holds K[kvperm(rr)]; source row permuted
#pragma unroll
    for (int i = 0; i < 4; ++i) {
      int Li = i * 8192 + tid * 16;
      int row = Li >> 9;
      int mi = row >> 4;
      int kvp = ((mi >> 1) << 5) | (((row >> 2) & 3) << 3) | ((mi & 1) << 2) | (row & 3);
      int kb = (Li & 511) ^ ((row & 7) << 4);
      GLL16((const char*)(Kb + (size_t)(kt * 64 + kvp) * 256) + kb, (char*)Ks + Li);
    }
    // stage V: linear copy of the pre-swizzled 32KB tile
    {
      const char* vsrc = Vb + ((size_t)kt << 15);
#pragma unroll
      for (int i = 0; i < 4; ++i) {
        int Li = i * 8192 + tid * 16;
        GLL16(vsrc + Li, (char*)Vt + Li);
      }
    }
    __syncthreads();

    // S^T = K * Q^T (rows = permuted kv, cols = q)
    f32x4 sacc[4];
#pragma unroll
    for (int mi = 0; mi < 4; ++mi) sacc[mi] = fz;
#pragma unroll
    for (int mi = 0; mi < 4; ++mi) {
      int row = mi * 16 + l15;
      int swz = (row & 7) << 4;
#pragma unroll
      for (int kc = 0; kc < 8; ++kc) {
        s16x8 kf = *(const s16x8*)((const char*)Ks + row * 512 + ((kc * 64 + g * 16) ^ swz));
        sacc[mi] = __builtin_amdgcn_mfma_f32_16x16x32_bf16(kf, qf[kc], sacc[mi], 0, 0, 0);
      }
    }
    // online softmax with defer-max (THR=8); kv-order-agnostic
    float sv[4][4];
    float mt = -__builtin_inff();
#pragma unroll
    for (int mi = 0; mi < 4; ++mi)
#pragma unroll
      for (int r = 0; r < 4; ++r) {
        float t = sacc[mi][r] * 0.0625f;
        sv[mi][r] = t;
        mt = fmaxf(mt, t);
      }
    mt = fmaxf(mt, __shfl_xor(mt, 16));
    mt = fmaxf(mt, __shfl_xor(mt, 32));
    if (!__all(mt <= m_run + 8.0f)) {
      float mnew = fmaxf(m_run, mt);
      float alpha = __expf(m_run - mnew);   // lane-local: q = l15 owns O^T cols
#pragma unroll
      for (int nd = 0; nd < 16; ++nd)
#pragma unroll
        for (int r = 0; r < 4; ++r) oacc[nd][r] *= alpha;
      l_run *= alpha;
      m_run = mnew;
    }
    float rs = 0.f;
#pragma unroll
    for (int mi = 0; mi < 4; ++mi)
#pragma unroll
      for (int r = 0; r < 4; ++r) {
        float p = __expf(sv[mi][r] - m_run);
        sv[mi][r] = p;
        rs += p;
      }
    rs += __shfl_xor(rs, 16);
    rs += __shfl_xor(rs, 32);
    l_run += rs;
    // pack P: pk[mi][rp] lane-local B-frag (P^T)
    unsigned int pk[4][2];
#pragma unroll
    for (int ni = 0; ni < 4; ++ni) {
      pk[ni][0] = (unsigned int)f2b(sv[ni][0]) | ((unsigned int)f2b(sv[ni][1]) << 16);
      pk[ni][1] = (unsigned int)f2b(sv[ni][2]) | ((unsigned int)f2b(sv[ni][3]) << 16);
    }
    // PV: O^T accum; A = V^T-frag from Vt, B = pk words
#pragma unroll
    for (int tt = 0; tt < 2; ++tt) {
      union { unsigned int u[4]; s16x8 v; } pf;
      pf.u[0] = pk[2 * tt][0];
      pf.u[1] = pk[2 * tt][1];
      pf.u[2] = pk[2 * tt + 1][0];
      pf.u[3] = pk[2 * tt + 1][1];
#pragma unroll
      for (int nd = 0; nd < 16; ++nd) {
        int d = nd * 16 + l15;
        s16x8 vf = *(const s16x8*)((const char*)Vt + d * 128 + ((tt * 64 + g * 16) ^ SWZV(d)));
        oacc[nd] = __builtin_amdgcn_mfma_f32_16x16x32_bf16(vf, pf.v, oacc[nd], 0, 0, 0);
      }
    }
  }
  // store normalized O directly to Ctx (b64 per nd); all lane-local
  float lf = 1.0f / l_run;
  const size_t base = (qrow) * 2048 + h * 256 + g * 4;
#pragma unroll
  for (int nd = 0; nd < 16; ++nd) {
    u16x4 o = { f2b(oacc[nd][0] * lf), f2b(oacc[nd][1] * lf),
                f2b(oacc[nd][2] * lf), f2b(oacc[nd][3] * lf) };
    *(u16x4*)(Ctx + base + nd * 16) = o;
  }
}

// ---------------------------------------------------------------- launch
extern "C" void kernel_launch(void* const* d_in, const int* in_sizes, int n_in,
                              void* d_out, int out_size, void* d_ws, size_t ws_size,
                              hipStream_t stream) {
  const float* x   = (const float*)d_in[0];
  const float* tk  = (const float*)d_in[1];
  const float* tv  = (const float*)d_in[2];
  const float* ln1 = (const float*)d_in[3];
  const float* ln2 = (const float*)d_in[4];
  const float* Wq  = (const float*)d_in[5];
  const float* Wk  = (const float*)d_in[6];
  const float* Wv  = (const float*)d_in[7];
  const float* Wo  = (const float*)d_in[8];
  const float* Wg  = (const float*)d_in[9];
  const float* Wu  = (const float*)d_in[10];
  const float* Wd  = (const float*)d_in[11];
  float* out = (float*)d_out;
  char* ws = (char*)d_ws;

  (void)hipFuncSetAttribute((const void*)gemm256<0>,
                            hipFuncAttributeMaxDynamicSharedMemorySize, 131072);
  (void)hipFuncSetAttribute((const void*)gemm256<1>,
                            hipFuncAttributeMaxDynamicSharedMemorySize, 131072);

  // workspace layout (126.1 MB, lifetime-based aliasing)
  unsigned short* tk_bf  = (unsigned short*)(ws + 0);
  unsigned short* tv_bf  = (unsigned short*)(ws + 8388608);
  unsigned short* vtg    = (unsigned short*)(ws + 0);         // V^T (tk/tv dead after K/V gemms)
  unsigned short* k_bf   = (unsigned short*)(ws + 16777216);
  unsigned short* v_bf   = (unsigned short*)(ws + 25165824);
  unsigned short* g_bf   = (unsigned short*)(ws + 0);         // FFN gate (vtg dead after attn)
  unsigned short* q_bf   = (unsigned short*)(ws + 33554432);
  unsigned short* ctx_bf = (unsigned short*)(ws + 50331648);
  float2*         rtab   = (float2*)(ws + 50331648);          // rope table (ctx dead until attn)
  unsigned short* u_bf   = (unsigned short*)(ws + 33554432);  // aliases q (dead)
  unsigned short* wq_bf  = (unsigned short*)(ws + 67108864);
  unsigned short* wk_bf  = (unsigned short*)(ws + 71303168);
  unsigned short* wv_bf  = (unsigned short*)(ws + 71434240);
  unsigned short* wo_bf  = (unsigned short*)(ws + 71565312);
  unsigned short* wg_bf  = (unsigned short*)(ws + 75759616);
  unsigned short* wu_bf  = (unsigned short*)(ws + 84148224);
  unsigned short* wd_bf  = (unsigned short*)(ws + 92536832);
  unsigned short* h_bf   = (unsigned short*)(ws + 100925440);
  float*          x2     = (float*)(ws + 109314048);

  dim3 blk(256);
  convert9<<<dim3(24704), blk, 0, stream>>>(
      Wq, Wk, Wv, Wo, Wg, Wu, Wd, tk, tv,
      wq_bf, wk_bf, wv_bf, wo_bf, wg_bf, wu_bf, wd_bf, tk_bf, tv_bf);

  rmsnorm_kernel<<<dim3(4096), blk, 0, stream>>>(x, ln1, h_bf);
  rope_table<<<dim3(256), blk, 0, stream>>>(rtab);
  gemm_nt<0, 1><<<dim3(16, 32), blk, 0, stream>>>(h_bf, wq_bf, nullptr, q_bf, 4096, 2048, 1024);
  rope_kernel<<<dim3(16384), blk, 0, stream>>>(q_bf, rtab);
  gemm_nt64<0, 1><<<dim3(2, 256), blk, 0, stream>>>(tk_bf, wk_bf, nullptr, k_bf, 16384, 256, 256);
  gemm_nt64<0, 1><<<dim3(2, 256), blk, 0, stream>>>(tv_bf, wv_bf, nullptr, v_bf, 16384, 256, 256);
  vtrans_kernel<<<dim3(32, 8), blk, 0, stream>>>(v_bf, vtg);
  attn_kernel<<<dim3(4, 8, 8), dim3(512), 0, stream>>>(q_bf, k_bf, vtg, ctx_bf);
  gemm_nt64<1, 0><<<dim3(8, 64), blk, 0, stream>>>(ctx_bf, wo_bf, x, x2, 4096, 1024, 2048);
  rmsnorm_kernel<<<dim3(4096), blk, 0, stream>>>(x2, ln2, h_bf);
  gemm256<0><<<dim3(16, 16), dim3(512), 131072, stream>>>(h_bf, wg_bf, nullptr, g_bf, 4096, 4096, 1024);
  gemm256<1><<<dim3(16, 16), dim3(512), 131072, stream>>>(h_bf, wu_bf, g_bf, g_bf, 4096, 4096, 1024);
  gemm_nt64<1, 0><<<dim3(8, 64), blk, 0, stream>>>(g_bf, wd_bf, x2, out, 4096, 1024, 4096);
}

// Round 17
// 349.310 us; speedup vs baseline: 2.0873x; 1.0305x over previous
//
#include <hip/hip_runtime.h>

typedef __attribute__((ext_vector_type(4))) float f32x4;
typedef __attribute__((ext_vector_type(8))) short s16x8;
typedef __attribute__((ext_vector_type(4))) unsigned short u16x4;

#define B_    8
#define L_    512
#define LC_   2048
#define EMBD  1024

__device__ __forceinline__ float b2f(unsigned short u) {
  unsigned int i = ((unsigned int)u) << 16;
  float f; __builtin_memcpy(&f, &i, 4); return f;
}
__device__ __forceinline__ unsigned short f2b(float f) {
  unsigned int i; __builtin_memcpy(&i, &f, 4);
  unsigned int r = i + 0x7FFFu + ((i >> 16) & 1u);
  return (unsigned short)(r >> 16);
}

#define GLL16(g, l)                                                         \
  __builtin_amdgcn_global_load_lds(                                         \
      (__attribute__((address_space(1))) void*)(g),                         \
      (__attribute__((address_space(3))) void*)(l), 16, 0, 0)

#define VMCNT6() asm volatile("s_waitcnt vmcnt(6)" ::: "memory")
#define VMCNT0() asm volatile("s_waitcnt vmcnt(0)" ::: "memory")
#define LGKM0()  asm volatile("s_waitcnt lgkmcnt(0)" ::: "memory")

// ---------------------------------------------------------------- converts (all 9 in one launch)
__global__ __launch_bounds__(256) void convert9(
    const float* s0, const float* s1, const float* s2, const float* s3,
    const float* s4, const float* s5, const float* s6, const float* s7,
    const float* s8,
    unsigned short* d0, unsigned short* d1, unsigned short* d2,
    unsigned short* d3, unsigned short* d4, unsigned short* d5,
    unsigned short* d6, unsigned short* d7, unsigned short* d8) {
  int bk = blockIdx.x;
  const float* s; unsigned short* d; int base;
  if      (bk <  2048) { s = s0; d = d0; base = 0; }
  else if (bk <  2112) { s = s1; d = d1; base = 2048; }
  else if (bk <  2176) { s = s2; d = d2; base = 2112; }
  else if (bk <  4224) { s = s3; d = d3; base = 2176; }
  else if (bk <  8320) { s = s4; d = d4; base = 4224; }
  else if (bk < 12416) { s = s5; d = d5; base = 8320; }
  else if (bk < 16512) { s = s6; d = d6; base = 12416; }
  else if (bk < 20608) { s = s7; d = d7; base = 16512; }
  else                 { s = s8; d = d8; base = 20608; }
  int i = (bk - base) * 256 + threadIdx.x;
  float4 v = ((const float4*)s)[i];
  u16x4 o = { f2b(v.x), f2b(v.y), f2b(v.z), f2b(v.w) };
  ((u16x4*)d)[i] = o;
}

// ---------------------------------------------------------------- rmsnorm
__global__ __launch_bounds__(256) void rmsnorm_kernel(
    const float* __restrict__ x, const float* __restrict__ w,
    unsigned short* __restrict__ out) {
  int row = blockIdx.x;
  int tid = threadIdx.x;
  float4 v = ((const float4*)(x + (size_t)row * EMBD))[tid];
  float ss = v.x*v.x + v.y*v.y + v.z*v.z + v.w*v.w;
#pragma unroll
  for (int o = 1; o < 64; o <<= 1) ss += __shfl_xor(ss, o);
  __shared__ float red[4];
  if ((tid & 63) == 0) red[tid >> 6] = ss;
  __syncthreads();
  float tot = red[0] + red[1] + red[2] + red[3];
  float rs = rsqrtf(tot * (1.0f / EMBD) + 1.1920928955078125e-07f);
  float4 wv = ((const float4*)w)[tid];
  u16x4 o = { f2b(v.x*rs*wv.x), f2b(v.y*rs*wv.y), f2b(v.z*rs*wv.z), f2b(v.w*rs*wv.w) };
  ((u16x4*)(out + (size_t)row * EMBD))[tid] = o;
}

// ---------------------------------------------------------------- rope table (unique (l,i) trig values)
__global__ __launch_bounds__(256) void rope_table(float2* __restrict__ tab) {
  int idx = blockIdx.x * 256 + threadIdx.x;   // 512*128
  int i = idx & 127, l = idx >> 7;
  float ts  = powf(10000.0f, (float)i * (2.0f / 256.0f));
  float rad = (float)l / ts;
  float s, c;
  sincosf(rad, &s, &c);
  tab[idx] = make_float2(c, s);
}

// ---------------------------------------------------------------- rope (in-place, table-driven; output pre-scaled by 1/16
// so attn's softmax input S = QK^T/16 needs no per-element scale)
__global__ __launch_bounds__(256) void rope_kernel(
    unsigned short* __restrict__ q, const float2* __restrict__ tab) {
  int idx = blockIdx.x * 256 + threadIdx.x;   // 4096*8*128
  int i   = idx & 127;
  int h   = (idx >> 7) & 7;
  int row = idx >> 10;
  int l   = row & (L_ - 1);
  size_t base = (size_t)row * 2048 + h * 256 + i;
  float x1 = b2f(q[base]);
  float x2 = b2f(q[base + 128]);
  float2 cs = tab[(l << 7) + i];
  q[base]       = f2b((x1 * cs.x - x2 * cs.y) * 0.0625f);
  q[base + 128] = f2b((x2 * cs.x + x1 * cs.y) * 0.0625f);
}

// ---------------------------------------------------------------- V transpose+swizzle to global (once)
#define SWZV(d) (((((d) & 7) ^ (((d) >> 3) & 7))) << 4)
__global__ __launch_bounds__(256) void vtrans_kernel(
    const unsigned short* __restrict__ V,   // [B][2048][256]
    unsigned short* __restrict__ VtG) {     // [B][32][32KB]
  const int kt = blockIdx.x, b = blockIdx.y;
  const int tid = threadIdx.x;
  const int dgrp = tid & 31, kvq = tid >> 5;
  const int d0 = dgrp * 8, kv0 = kvq * 8;
  const unsigned short* vp = V + ((size_t)b * LC_ + kt * 64 + kv0) * 256 + d0;
  s16x8 r[8];
#pragma unroll
  for (int jj = 0; jj < 8; ++jj) r[jj] = *(const s16x8*)(vp + jj * 256);
  char* tb = (char*)VtG + (((size_t)b * 32 + kt) << 15);
#pragma unroll
  for (int j = 0; j < 8; ++j) {
    int d = d0 + j;
    union { unsigned int u[4]; s16x8 v; } w;
#pragma unroll
    for (int p = 0; p < 4; ++p)
      w.u[p] = (unsigned int)(unsigned short)r[2 * p][j] |
               ((unsigned int)(unsigned short)r[2 * p + 1][j] << 16);
    *(s16x8*)(tb + d * 128 + ((kv0 * 2) ^ SWZV(d))) = w.v;
  }
}

// ---------------------------------------------------------------- NT GEMM 128x128 (2-barrier)
template <int ADD_RES, int OUT_BF16>
__global__ __launch_bounds__(256, 2) void gemm_nt(
    const unsigned short* __restrict__ A, const unsigned short* __restrict__ Bw,
    const float* __restrict__ Res, void* __restrict__ C, int M, int N, int K) {
  __shared__ unsigned short As[128 * 64];
  __shared__ unsigned short Bs[128 * 64];
  const int tid = threadIdx.x;
  const int lane = tid & 63, wid = tid >> 6;
  const int l15 = lane & 15, l4 = lane >> 4;
  const int wr = wid >> 1, wc = wid & 1;
  const int m0 = blockIdx.y * 128, n0 = blockIdx.x * 128;

  const f32x4 fz = {0.f, 0.f, 0.f, 0.f};
  f32x4 acc[4][4];
#pragma unroll
  for (int i = 0; i < 4; ++i)
#pragma unroll
    for (int j = 0; j < 4; ++j) acc[i][j] = fz;

  for (int k0 = 0; k0 < K; k0 += 64) {
    __syncthreads();
#pragma unroll
    for (int i = 0; i < 4; ++i) {
      int Li = i * 4096 + tid * 16;
      int row = Li >> 7;
      int kb = (Li & 127) ^ ((row & 7) << 4);
      GLL16((const char*)(A + (size_t)(m0 + row) * K + k0) + kb, (char*)As + Li);
      GLL16((const char*)(Bw + (size_t)(n0 + row) * K + k0) + kb, (char*)Bs + Li);
    }
    __syncthreads();
#pragma unroll
    for (int kk = 0; kk < 2; ++kk) {
      s16x8 af[4], bfr[4];
#pragma unroll
      for (int mi = 0; mi < 4; ++mi) {
        int row = wr * 64 + mi * 16 + l15;
        int kb = (kk * 64 + l4 * 16) ^ ((row & 7) << 4);
        af[mi] = *(const s16x8*)((const char*)As + row * 128 + kb);
      }
#pragma unroll
      for (int ni = 0; ni < 4; ++ni) {
        int row = wc * 64 + ni * 16 + l15;
        int kb = (kk * 64 + l4 * 16) ^ ((row & 7) << 4);
        bfr[ni] = *(const s16x8*)((const char*)Bs + row * 128 + kb);
      }
#pragma unroll
      for (int mi = 0; mi < 4; ++mi)
#pragma unroll
        for (int ni = 0; ni < 4; ++ni)
          acc[mi][ni] = __builtin_amdgcn_mfma_f32_16x16x32_bf16(
              af[mi], bfr[ni], acc[mi][ni], 0, 0, 0);
    }
  }
#pragma unroll
  for (int mi = 0; mi < 4; ++mi) {
#pragma unroll
    for (int r = 0; r < 4; ++r) {
      int grow = m0 + wr * 64 + mi * 16 + l4 * 4 + r;
      size_t base = (size_t)grow * N + n0 + wc * 64 + l15;
#pragma unroll
      for (int ni = 0; ni < 4; ++ni) {
        float v = acc[mi][ni][r];
        size_t idx = base + ni * 16;
        if (ADD_RES) v += Res[idx];
        if (OUT_BF16) ((unsigned short*)C)[idx] = f2b(v);
        else          ((float*)C)[idx] = v;
      }
    }
  }
}

// ---------------------------------------------------------------- NT GEMM 64x128 (512-block grids, 2/CU)
template <int ADD_RES, int OUT_BF16>
__global__ __launch_bounds__(256, 2) void gemm_nt64(
    const unsigned short* __restrict__ A, const unsigned short* __restrict__ Bw,
    const float* __restrict__ Res, void* __restrict__ C, int M, int N, int K) {
  __shared__ unsigned short As[64 * 64];
  __shared__ unsigned short Bs[128 * 64];
  const int tid = threadIdx.x;
  const int lane = tid & 63, wid = tid >> 6;
  const int l15 = lane & 15, l4 = lane >> 4;
  const int wr = wid >> 1, wc = wid & 1;
  const int m0 = blockIdx.y * 64, n0 = blockIdx.x * 128;

  const f32x4 fz = {0.f, 0.f, 0.f, 0.f};
  f32x4 acc[2][4];
#pragma unroll
  for (int i = 0; i < 2; ++i)
#pragma unroll
    for (int j = 0; j < 4; ++j) acc[i][j] = fz;

  for (int k0 = 0; k0 < K; k0 += 64) {
    __syncthreads();
#pragma unroll
    for (int i = 0; i < 2; ++i) {
      int Li = i * 4096 + tid * 16;
      int row = Li >> 7;
      int kb = (Li & 127) ^ ((row & 7) << 4);
      GLL16((const char*)(A + (size_t)(m0 + row) * K + k0) + kb, (char*)As + Li);
    }
#pragma unroll
    for (int i = 0; i < 4; ++i) {
      int Li = i * 4096 + tid * 16;
      int row = Li >> 7;
      int kb = (Li & 127) ^ ((row & 7) << 4);
      GLL16((const char*)(Bw + (size_t)(n0 + row) * K + k0) + kb, (char*)Bs + Li);
    }
    __syncthreads();
#pragma unroll
    for (int kk = 0; kk < 2; ++kk) {
      s16x8 af[2], bfr[4];
#pragma unroll
      for (int mi = 0; mi < 2; ++mi) {
        int row = wr * 32 + mi * 16 + l15;
        int kb = (kk * 64 + l4 * 16) ^ ((row & 7) << 4);
        af[mi] = *(const s16x8*)((const char*)As + row * 128 + kb);
      }
#pragma unroll
      for (int ni = 0; ni < 4; ++ni) {
        int row = wc * 64 + ni * 16 + l15;
        int kb = (kk * 64 + l4 * 16) ^ ((row & 7) << 4);
        bfr[ni] = *(const s16x8*)((const char*)Bs + row * 128 + kb);
      }
#pragma unroll
      for (int mi = 0; mi < 2; ++mi)
#pragma unroll
        for (int ni = 0; ni < 4; ++ni)
          acc[mi][ni] = __builtin_amdgcn_mfma_f32_16x16x32_bf16(
              af[mi], bfr[ni], acc[mi][ni], 0, 0, 0);
    }
  }
#pragma unroll
  for (int mi = 0; mi < 2; ++mi) {
#pragma unroll
    for (int r = 0; r < 4; ++r) {
      int grow = m0 + wr * 32 + mi * 16 + l4 * 4 + r;
      size_t base = (size_t)grow * N + n0 + wc * 64 + l15;
#pragma unroll
      for (int ni = 0; ni < 4; ++ni) {
        float v = acc[mi][ni][r];
        size_t idx = base + ni * 16;
        if (ADD_RES) v += Res[idx];
        if (OUT_BF16) ((unsigned short*)C)[idx] = f2b(v);
        else          ((float*)C)[idx] = v;
      }
    }
  }
}

// ---------------------------------------------------------------- 256x256 8-phase GEMM (T1..T5; optional fused silu(g)*acc)
template <int SWIGLU>
__global__ __launch_bounds__(512, 2) void gemm256(
    const unsigned short* __restrict__ A, const unsigned short* __restrict__ Bw,
    const unsigned short* __restrict__ G, unsigned short* __restrict__ C,
    int M, int N, int K) {
  extern __shared__ char smem[];
  const int tid = threadIdx.x;
  const int lane = tid & 63;
  const int wid = tid >> 6;
  const int wr = wid >> 2, wc = wid & 3;
  const int l15 = lane & 15, g = lane >> 4;
  int flat = blockIdx.y * 16 + blockIdx.x;
  flat = (flat & 7) * 32 + (flat >> 3);
  const int m0 = (flat >> 4) * 256, n0 = (flat & 15) * 256;
  const int T = K >> 6;
  const int swz = (l15 & 7) << 4;

  auto stage = [&](int t, int mat, int half) {
    char* dst = smem + mat * 65536 + (t & 1) * 32768 + half * 16384;
    const unsigned short* src = (mat ? Bw + (size_t)(n0 + half * 128) * K
                                     : A + (size_t)(m0 + half * 128) * K) + t * 64;
#pragma unroll
    for (int i = 0; i < 2; ++i) {
      int Li = i * 8192 + tid * 16;
      int row = Li >> 7;
      int kb = (Li & 127) ^ ((row & 7) << 4);
      GLL16((const char*)(src + (size_t)row * K) + kb, dst + Li);
    }
  };

  const f32x4 fz = {0.f, 0.f, 0.f, 0.f};
  f32x4 acc[2][2][4][2];
#pragma unroll
  for (int ms = 0; ms < 2; ++ms)
#pragma unroll
    for (int ns = 0; ns < 2; ++ns)
#pragma unroll
      for (int mi = 0; mi < 4; ++mi)
#pragma unroll
        for (int ni = 0; ni < 2; ++ni) acc[ms][ns][mi][ni] = fz;

  stage(0, 1, 0); stage(0, 1, 1); stage(0, 0, 0); stage(0, 0, 1);
  stage(1, 1, 0); stage(1, 1, 1); stage(1, 0, 0);
  VMCNT6();
  __builtin_amdgcn_s_barrier();

  for (int t = 0; t < T; ++t) {
    char* Ab = smem + (t & 1) * 32768 + wr * 16384;
    char* Bb = smem + 65536 + (t & 1) * 32768 + (wc >> 1) * 16384;
    const int bn = (wc & 1) * 64;
    s16x8 a[4][2], b0[2][2], b1[2][2];

#pragma unroll
    for (int mi = 0; mi < 4; ++mi) {
      int row = mi * 16 + l15;
#pragma unroll
      for (int kk = 0; kk < 2; ++kk)
        a[mi][kk] = *(const s16x8*)(Ab + row * 128 + ((kk * 64 + g * 16) ^ swz));
    }
#pragma unroll
    for (int ni = 0; ni < 2; ++ni) {
      int r0 = (bn + ni * 16 + l15) * 128;
      int r1 = (bn + 32 + ni * 16 + l15) * 128;
#pragma unroll
      for (int kk = 0; kk < 2; ++kk) {
        int ko = (kk * 64 + g * 16) ^ swz;
        b0[ni][kk] = *(const s16x8*)(Bb + r0 + ko);
        b1[ni][kk] = *(const s16x8*)(Bb + r1 + ko);
      }
    }
    if (t + 1 < T) stage(t + 1, 0, 1);
    __builtin_amdgcn_s_barrier();
    LGKM0();
    __builtin_amdgcn_sched_barrier(0);
    __builtin_amdgcn_s_setprio(1);
#pragma unroll
    for (int mi = 0; mi < 4; ++mi)
#pragma unroll
      for (int ni = 0; ni < 2; ++ni)
#pragma unroll
        for (int kk = 0; kk < 2; ++kk)
          acc[0][0][mi][ni] = __builtin_amdgcn_mfma_f32_16x16x32_bf16(
              a[mi][kk], b0[ni][kk], acc[0][0][mi][ni], 0, 0, 0);
    __builtin_amdgcn_s_setprio(0);
    __builtin_amdgcn_s_barrier();

    if (t + 2 < T) stage(t + 2, 1, 0);
    __builtin_amdgcn_s_barrier();
    __builtin_amdgcn_s_setprio(1);
#pragma unroll
    for (int mi = 0; mi < 4; ++mi)
#pragma unroll
      for (int ni = 0; ni < 2; ++ni)
#pragma unroll
        for (int kk = 0; kk < 2; ++kk)
          acc[0][1][mi][ni] = __builtin_amdgcn_mfma_f32_16x16x32_bf16(
              a[mi][kk], b1[ni][kk], acc[0][1][mi][ni], 0, 0, 0);
    __builtin_amdgcn_s_setprio(0);
    __builtin_amdgcn_s_barrier();

#pragma unroll
    for (int mi = 0; mi < 4; ++mi) {
      int row = 64 + mi * 16 + l15;
#pragma unroll
      for (int kk = 0; kk < 2; ++kk)
        a[mi][kk] = *(const s16x8*)(Ab + row * 128 + ((kk * 64 + g * 16) ^ swz));
    }
    if (t + 2 < T) stage(t + 2, 1, 1);
    __builtin_amdgcn_s_barrier();
    LGKM0();
    __builtin_amdgcn_sched_barrier(0);
    __builtin_amdgcn_s_setprio(1);
#pragma unroll
    for (int mi = 0; mi < 4; ++mi)
#pragma unroll
      for (int ni = 0; ni < 2; ++ni)
#pragma unroll
        for (int kk = 0; kk < 2; ++kk)
          acc[1][0][mi][ni] = __builtin_amdgcn_mfma_f32_16x16x32_bf16(
              a[mi][kk], b0[ni][kk], acc[1][0][mi][ni], 0, 0, 0);
    __builtin_amdgcn_s_setprio(0);
    __builtin_amdgcn_s_barrier();

    if (t + 2 < T) { stage(t + 2, 0, 0); VMCNT6(); }
    else           { VMCNT0(); }
    __builtin_amdgcn_s_barrier();
    __builtin_amdgcn_s_setprio(1);
#pragma unroll
    for (int mi = 0; mi < 4; ++mi)
#pragma unroll
      for (int ni = 0; ni < 2; ++ni)
#pragma unroll
        for (int kk = 0; kk < 2; ++kk)
          acc[1][1][mi][ni] = __builtin_amdgcn_mfma_f32_16x16x32_bf16(
              a[mi][kk], b1[ni][kk], acc[1][1][mi][ni], 0, 0, 0);
    __builtin_amdgcn_s_setprio(0);
    __builtin_amdgcn_s_barrier();
  }

#pragma unroll
  for (int ms = 0; ms < 2; ++ms)
#pragma unroll
    for (int mi = 0; mi < 4; ++mi)
#pragma unroll
      for (int r = 0; r < 4; ++r) {
        int grow = m0 + wr * 128 + ms * 64 + mi * 16 + g * 4 + r;
        size_t base = (size_t)grow * N + n0 + wc * 64;
#pragma unroll
        for (int ns = 0; ns < 2; ++ns)
#pragma unroll
          for (int ni = 0; ni < 2; ++ni) {
            size_t idx = base + ns * 32 + ni * 16 + l15;
            float v = acc[ms][ns][mi][ni][r];
            if (SWIGLU) {
              float gf = b2f(G[idx]);
              v *= gf / (1.0f + __expf(-gf));
            }
            C[idx] = f2b(v);
          }
      }
}

// ---------------------------------------------------------------- fused attention (O^T, zero-shuffle, GLL16 dbuf)
// grid (qt=4, h=8, b=8) = 256 blocks, 512 thr (8 waves x 16 q-rows), 32 KV
// tiles/block. LDS 128KB double-buffered: issue all 8 GLL16s for tile t+1
// BEFORE compute(t) (staging is pure GLL16 -> no regs live across compute);
// ONE vmcnt(0)+barrier per tile. K staged with PERMUTED source rows so packed
// P words form the PV B-frag; O^T keeps q=l15 lane-local. Q pre-scaled 1/16.
__global__ __launch_bounds__(512, 2) void attn_kernel(
    const unsigned short* __restrict__ Q,    // [4096][2048] (roped, x1/16)
    const unsigned short* __restrict__ Kc,   // [B][2048][256]
    const unsigned short* __restrict__ VtG,  // [B][32][32KB] pre-swizzled
    unsigned short* __restrict__ Ctx) {      // [4096][2048]
  extern __shared__ char ats[];   // Ks[2] 2x32KB @0 | Vt[2] 2x32KB @64KB
  const int tid = threadIdx.x;
  const int lane = tid & 63, wid = tid >> 6;
  const int l15 = lane & 15, g = lane >> 4;
  const int qt = blockIdx.x, h = blockIdx.y, b = blockIdx.z;

  const size_t qrow = (size_t)(b * L_ + qt * 128 + wid * 16 + l15);
  const unsigned short* qp = Q + qrow * 2048 + h * 256;
  s16x8 qf[8];
#pragma unroll
  for (int kc = 0; kc < 8; ++kc) qf[kc] = *(const s16x8*)(qp + kc * 32 + g * 8);

  const f32x4 fz = {0.f, 0.f, 0.f, 0.f};
  f32x4 oacc[16];   // O^T: oacc[nd][r] = O[q=l15][d = nd*16 + g*4 + r]
#pragma unroll
  for (int i = 0; i < 16; ++i) oacc[i] = fz;
  float m_run = -__builtin_inff(), l_run = 0.f;

  const unsigned short* Kb = Kc + (size_t)b * LC_ * 256;
  const char* Vb = (const char*)VtG + ((size_t)b << 20);

  auto stage = [&](int kt, int buf) {
    char* dstK = ats + buf * 32768;
    char* dstV = ats + 65536 + buf * 32768;
    const char* vsrc = Vb + ((size_t)kt << 15);
#pragma unroll
    for (int i = 0; i < 4; ++i) {
      int Li = i * 8192 + tid * 16;
      int row = Li >> 9;
      int mi = row >> 4;
      int kvp = ((mi >> 1) << 5) | (((row >> 2) & 3) << 3) | ((mi & 1) << 2) | (row & 3);
      int kb = (Li & 511) ^ ((row & 7) << 4);
      GLL16((const char*)(Kb + (size_t)(kt * 64 + kvp) * 256) + kb, dstK + Li);
      GLL16(vsrc + Li, dstV + Li);
    }
  };

  // prologue: tile 0 -> buffer 0
  stage(0, 0);
  VMCNT0();
  __syncthreads();

  for (int kt = 0; kt < LC_ / 64; ++kt) {
    const int cur = kt & 1;
    const bool more = (kt + 1 < LC_ / 64);
    if (more) stage(kt + 1, cur ^ 1);
    const char* KsB = ats + cur * 32768;
    const char* VtB = ats + 65536 + cur * 32768;

    // S^T = K * Q^T (rows = permuted kv, cols = q); Q pre-scaled by 1/16
    f32x4 sacc[4];
#pragma unroll
    for (int mi = 0; mi < 4; ++mi) sacc[mi] = fz;
#pragma unroll
    for (int mi = 0; mi < 4; ++mi) {
      int row = mi * 16 + l15;
      int swz = (row & 7) << 4;
#pragma unroll
      for (int kc = 0; kc < 8; ++kc) {
        s16x8 kf = *(const s16x8*)(KsB + row * 512 + ((kc * 64 + g * 16) ^ swz));
        sacc[mi] = __builtin_amdgcn_mfma_f32_16x16x32_bf16(kf, qf[kc], sacc[mi], 0, 0, 0);
      }
    }
    // online softmax with defer-max (THR=8)
    float sv[4][4];
    float mt = -__builtin_inff();
#pragma unroll
    for (int mi = 0; mi < 4; ++mi)
#pragma unroll
      for (int r = 0; r < 4; ++r) {
        sv[mi][r] = sacc[mi][r];
        mt = fmaxf(mt, sacc[mi][r]);
      }
    mt = fmaxf(mt, __shfl_xor(mt, 16));
    mt = fmaxf(mt, __shfl_xor(mt, 32));
    if (!__all(mt <= m_run + 8.0f)) {
      float mnew = fmaxf(m_run, mt);
      float alpha = __expf(m_run - mnew);   // lane-local: q = l15 owns O^T cols
#pragma unroll
      for (int nd = 0; nd < 16; ++nd)
#pragma unroll
        for (int r = 0; r < 4; ++r) oacc[nd][r] *= alpha;
      l_run *= alpha;
      m_run = mnew;
    }
    float rs = 0.f;
#pragma unroll
    for (int mi = 0; mi < 4; ++mi)
#pragma unroll
      for (int r = 0; r < 4; ++r) {
        float p = __expf(sv[mi][r] - m_run);
        sv[mi][r] = p;
        rs += p;
      }
    rs += __shfl_xor(rs, 16);
    rs += __shfl_xor(rs, 32);
    l_run += rs;
    // pack P: lane-local B-frag (P^T)
    unsigned int pk[4][2];
#pragma unroll
    for (int ni = 0; ni < 4; ++ni) {
      pk[ni][0] = (unsigned int)f2b(sv[ni][0]) | ((unsigned int)f2b(sv[ni][1]) << 16);
      pk[ni][1] = (unsigned int)f2b(sv[ni][2]) | ((unsigned int)f2b(sv[ni][3]) << 16);
    }
    // PV: O^T accum; A = V^T-frag from Vt, B = pk words
#pragma unroll
    for (int tt = 0; tt < 2; ++tt) {
      union { unsigned int u[4]; s16x8 v; } pf;
      pf.u[0] = pk[2 * tt][0];
      pf.u[1] = pk[2 * tt][1];
      pf.u[2] = pk[2 * tt + 1][0];
      pf.u[3] = pk[2 * tt + 1][1];
#pragma unroll
      for (int nd = 0; nd < 16; ++nd) {
        int d = nd * 16 + l15;
        s16x8 vf = *(const s16x8*)(VtB + d * 128 + ((tt * 64 + g * 16) ^ SWZV(d)));
        oacc[nd] = __builtin_amdgcn_mfma_f32_16x16x32_bf16(vf, pf.v, oacc[nd], 0, 0, 0);
      }
    }

    if (more) { VMCNT0(); __syncthreads(); }
  }
  // store normalized O directly to Ctx (b64 per nd); all lane-local
  float lf = 1.0f / l_run;
  const size_t base = (qrow) * 2048 + h * 256 + g * 4;
#pragma unroll
  for (int nd = 0; nd < 16; ++nd) {
    u16x4 o = { f2b(oacc[nd][0] * lf), f2b(oacc[nd][1] * lf),
                f2b(oacc[nd][2] * lf), f2b(oacc[nd][3] * lf) };
    *(u16x4*)(Ctx + base + nd * 16) = o;
  }
}

// ---------------------------------------------------------------- launch
extern "C" void kernel_launch(void* const* d_in, const int* in_sizes, int n_in,
                              void* d_out, int out_size, void* d_ws, size_t ws_size,
                              hipStream_t stream) {
  const float* x   = (const float*)d_in[0];
  const float* tk  = (const float*)d_in[1];
  const float* tv  = (const float*)d_in[2];
  const float* ln1 = (const float*)d_in[3];
  const float* ln2 = (const float*)d_in[4];
  const float* Wq  = (const float*)d_in[5];
  const float* Wk  = (const float*)d_in[6];
  const float* Wv  = (const float*)d_in[7];
  const float* Wo  = (const float*)d_in[8];
  const float* Wg  = (const float*)d_in[9];
  const float* Wu  = (const float*)d_in[10];
  const float* Wd  = (const float*)d_in[11];
  float* out = (float*)d_out;
  char* ws = (char*)d_ws;

  (void)hipFuncSetAttribute((const void*)gemm256<0>,
                            hipFuncAttributeMaxDynamicSharedMemorySize, 131072);
  (void)hipFuncSetAttribute((const void*)gemm256<1>,
                            hipFuncAttributeMaxDynamicSharedMemorySize, 131072);
  (void)hipFuncSetAttribute((const void*)attn_kernel,
                            hipFuncAttributeMaxDynamicSharedMemorySize, 131072);

  // workspace layout (126.1 MB, lifetime-based aliasing)
  unsigned short* tk_bf  = (unsigned short*)(ws + 0);
  unsigned short* tv_bf  = (unsigned short*)(ws + 8388608);
  unsigned short* vtg    = (unsigned short*)(ws + 0);         // V^T (tk/tv dead after K/V gemms)
  unsigned short* k_bf   = (unsigned short*)(ws + 16777216);
  unsigned short* v_bf   = (unsigned short*)(ws + 25165824);
  unsigned short* g_bf   = (unsigned short*)(ws + 0);         // FFN gate (vtg dead after attn)
  unsigned short* q_bf   = (unsigned short*)(ws + 33554432);
  unsigned short* ctx_bf = (unsigned short*)(ws + 50331648);
  float2*         rtab   = (float2*)(ws + 50331648);          // rope table (ctx dead until attn)
  unsigned short* u_bf   = (unsigned short*)(ws + 33554432);  // aliases q (dead)
  unsigned short* wq_bf  = (unsigned short*)(ws + 67108864);
  unsigned short* wk_bf  = (unsigned short*)(ws + 71303168);
  unsigned short* wv_bf  = (unsigned short*)(ws + 71434240);
  unsigned short* wo_bf  = (unsigned short*)(ws + 71565312);
  unsigned short* wg_bf  = (unsigned short*)(ws + 75759616);
  unsigned short* wu_bf  = (unsigned short*)(ws + 84148224);
  unsigned short* wd_bf  = (unsigned short*)(ws + 92536832);
  unsigned short* h_bf   = (unsigned short*)(ws + 100925440);
  float*          x2     = (float*)(ws + 109314048);

  dim3 blk(256);
  convert9<<<dim3(24704), blk, 0, stream>>>(
      Wq, Wk, Wv, Wo, Wg, Wu, Wd, tk, tv,
      wq_bf, wk_bf, wv_bf, wo_bf, wg_bf, wu_bf, wd_bf, tk_bf, tv_bf);

  rmsnorm_kernel<<<dim3(4096), blk, 0, stream>>>(x, ln1, h_bf);
  rope_table<<<dim3(256), blk, 0, stream>>>(rtab);
  gemm_nt<0, 1><<<dim3(16, 32), blk, 0, stream>>>(h_bf, wq_bf, nullptr, q_bf, 4096, 2048, 1024);
  rope_kernel<<<dim3(16384), blk, 0, stream>>>(q_bf, rtab);
  gemm_nt64<0, 1><<<dim3(2, 256), blk, 0, stream>>>(tk_bf, wk_bf, nullptr, k_bf, 16384, 256, 256);
  gemm_nt64<0, 1><<<dim3(2, 256), blk, 0, stream>>>(tv_bf, wv_bf, nullptr, v_bf, 16384, 256, 256);
  vtrans_kernel<<<dim3(32, 8), blk, 0, stream>>>(v_bf, vtg);
  attn_kernel<<<dim3(4, 8, 8), dim3(512), 131072, stream>>>(q_bf, k_bf, vtg, ctx_bf);
  gemm_nt64<1, 0><<<dim3(8, 64), blk, 0, stream>>>(ctx_bf, wo_bf, x, x2, 4096, 1024, 2048);
  rmsnorm_kernel<<<dim3(4096), blk, 0, stream>>>(x2, ln2, h_bf);
  gemm256<0><<<dim3(16, 16), dim3(512), 131072, stream>>>(h_bf, wg_bf, nullptr, g_bf, 4096, 4096, 1024);
  gemm256<1><<<dim3(16, 16), dim3(512), 131072, stream>>>(h_bf, wu_bf, g_bf, g_bf, 4096, 4096, 1024);
  gemm_nt64<1, 0><<<dim3(8, 64), blk, 0, stream>>>(g_bf, wd_bf, x2, out, 4096, 1024, 4096);
}